// Round 10
// baseline (2960.528 us; speedup 1.0000x reference)
//
#include <hip/hip_runtime.h>
#include <stdint.h>

#define BB 4
#define NN 8192
#define KK 16
#define BN (BB*NN)        // 32768
#define BNK (BN*KK)       // 524288

#define G   48
#define G3  (G*G*G)       // 110592
#define G3P (G3+8)        // padded; starts[G3] = NN sentinel

// ---------------- K0: pack xyz -> (x,y,z,|p|^2) float4 ----------------
__global__ void k_xyzw(const float* __restrict__ xyz1, const float* __restrict__ xyz2,
                       float4* __restrict__ w1, float4* __restrict__ w2){
    int t = blockIdx.x*256 + threadIdx.x;
    if (t >= 2*BN) return;
    const float* src; float4* dst; int i;
    if (t < BN){ src = xyz1; dst = w1; i = t; }
    else       { src = xyz2; dst = w2; i = t - BN; }
    int b = i >> 13, m = i & (NN-1);
    const float* p = src + (size_t)b*3*NN + m;
    float x = p[0], y = p[NN], z = p[2*NN];
    dst[i] = make_float4(x, y, z, x*x + y*y + z*z);
}

// ------------- K1: A[b,n,co] = bias[co] + sum_ci W1[co][colOff+ci]*feat[b,ci,n] -------------
__global__ __launch_bounds__(64) void k_prefeat(const float* __restrict__ feat,
                                                const float* __restrict__ W1,
                                                const float* __restrict__ bias, int colOff,
                                                float* __restrict__ out){
    __shared__ float Wt[64*64];   // [ci][co]
    __shared__ float bsh[64];
    int t = threadIdx.x;
    for (int ci = 0; ci < 64; ++ci)
        Wt[ci*64 + t] = W1[t*131 + colOff + ci];   // thread t = row co
    bsh[t] = bias ? bias[t] : 0.0f;
    __syncthreads();

    int col = blockIdx.x*64 + t;       // (b,n) flat
    int b = col >> 13, n = col & (NN-1);
    const float* f = feat + (size_t)b*64*NN + n;
    float acc[64];
    #pragma unroll
    for (int co = 0; co < 64; ++co) acc[co] = 0.f;
    for (int ci = 0; ci < 64; ++ci){
        float v = f[(size_t)ci*NN];
        const float4* wrow = (const float4*)(Wt + ci*64);
        #pragma unroll
        for (int c4 = 0; c4 < 16; ++c4){
            float4 w = wrow[c4];
            acc[c4*4+0] = fmaf(w.x, v, acc[c4*4+0]);
            acc[c4*4+1] = fmaf(w.y, v, acc[c4*4+1]);
            acc[c4*4+2] = fmaf(w.z, v, acc[c4*4+2]);
            acc[c4*4+3] = fmaf(w.w, v, acc[c4*4+3]);
        }
    }
    float4* o = (float4*)(out + (size_t)col*64);
    const float4* bs = (const float4*)bsh;
    #pragma unroll
    for (int c4 = 0; c4 < 16; ++c4){
        float4 bb = bs[c4];
        o[c4] = make_float4(acc[c4*4+0]+bb.x, acc[c4*4+1]+bb.y,
                            acc[c4*4+2]+bb.z, acc[c4*4+3]+bb.w);
    }
}

// ================= grid-binned exact 16-NN =================
__device__ __forceinline__ unsigned mono_f32(float f){
    unsigned u = __float_as_uint(f);
    return ((int)u >= 0) ? (u | 0x80000000u) : ~u;
}
__device__ __forceinline__ float unmono_f32(unsigned v){
    unsigned u = ((int)v < 0) ? (v & 0x7FFFFFFFu) : ~v;
    return __uint_as_float(u);
}
__device__ __forceinline__ unsigned long long mono_f64(double d){
    unsigned long long u = (unsigned long long)__double_as_longlong(d);
    return ((long long)u >= 0) ? (u | 0x8000000000000000ull) : ~u;
}
__device__ __forceinline__ double unmono_f64(unsigned long long v){
    unsigned long long u = ((long long)v < 0) ? (v & 0x7FFFFFFFFFFFFFFFull) : ~v;
    return __longlong_as_double((long long)u);
}

__device__ __forceinline__ void cell_of(float x, float y, float z,
                                        const unsigned* bmin, const unsigned* bmax, int seg,
                                        int& cx, int& cy, int& cz){
    int s3 = seg*3;
    float mnx = unmono_f32(bmin[s3+0]), mny = unmono_f32(bmin[s3+1]), mnz = unmono_f32(bmin[s3+2]);
    float mxx = unmono_f32(bmax[s3+0]), mxy = unmono_f32(bmax[s3+1]), mxz = unmono_f32(bmax[s3+2]);
    float ivx = (float)G/(mxx-mnx), ivy = (float)G/(mxy-mny), ivz = (float)G/(mxz-mnz);
    cx = (int)((x-mnx)*ivx); cx = cx < 0 ? 0 : (cx > G-1 ? G-1 : cx);
    cy = (int)((y-mny)*ivy); cy = cy < 0 ? 0 : (cy > G-1 ? G-1 : cy);
    cz = (int)((z-mnz)*ivz); cz = cz < 0 ? 0 : (cz > G-1 ? G-1 : cz);
}

// K2a: per-(cloud,batch) coordinate bounds via wave-reduce + atomics
__global__ __launch_bounds__(256) void k_bounds(const float4* __restrict__ w1, const float4* __restrict__ w2,
                                                unsigned* __restrict__ bmin, unsigned* __restrict__ bmax){
    int t = blockIdx.x*256 + threadIdx.x;     // 2*BN
    int cloud = (t >= BN) ? 1 : 0;
    int i = cloud ? t - BN : t;
    float4 p = (cloud ? w2 : w1)[i];
    float mn0 = p.x, mn1 = p.y, mn2 = p.z;
    float mx0 = p.x, mx1 = p.y, mx2 = p.z;
    #pragma unroll
    for (int d = 1; d < 64; d <<= 1){
        mn0 = fminf(mn0, __shfl_xor(mn0, d)); mx0 = fmaxf(mx0, __shfl_xor(mx0, d));
        mn1 = fminf(mn1, __shfl_xor(mn1, d)); mx1 = fmaxf(mx1, __shfl_xor(mx1, d));
        mn2 = fminf(mn2, __shfl_xor(mn2, d)); mx2 = fmaxf(mx2, __shfl_xor(mx2, d));
    }
    if ((threadIdx.x & 63) == 0){
        int seg = cloud*4 + (i >> 13), s3 = seg*3;
        atomicMin(&bmin[s3+0], mono_f32(mn0)); atomicMax(&bmax[s3+0], mono_f32(mx0));
        atomicMin(&bmin[s3+1], mono_f32(mn1)); atomicMax(&bmax[s3+1], mono_f32(mx1));
        atomicMin(&bmin[s3+2], mono_f32(mn2)); atomicMax(&bmax[s3+2], mono_f32(mx2));
    }
}

// K2b: histogram points into cells
__global__ __launch_bounds__(256) void k_count(const float4* __restrict__ w1, const float4* __restrict__ w2,
                                               const unsigned* __restrict__ bmin, const unsigned* __restrict__ bmax,
                                               int* __restrict__ counts){
    int t = blockIdx.x*256 + threadIdx.x;     // 2*BN
    int cloud = (t >= BN) ? 1 : 0;
    int i = cloud ? t - BN : t;
    float4 p = (cloud ? w2 : w1)[i];
    int seg = cloud*4 + (i >> 13);
    int cx, cy, cz;
    cell_of(p.x, p.y, p.z, bmin, bmax, seg, cx, cy, cz);
    atomicAdd(&counts[seg*G3P + (cz*G + cy)*G + cx], 1);
}

// K2c: exclusive prefix scan per segment (1024 threads, 108 cells each)
__global__ __launch_bounds__(1024) void k_scan(const int* __restrict__ counts,
                                               int* __restrict__ starts, int* __restrict__ offsets){
    __shared__ int part[1024];
    int seg = blockIdx.x;
    const int* c = counts + (size_t)seg*G3P;
    int* st = starts + (size_t)seg*G3P;
    int* of = offsets + (size_t)seg*G3P;
    int t = threadIdx.x;
    int base = t*108;
    int s = 0;
    for (int i = 0; i < 108; ++i) s += c[base+i];
    part[t] = s;
    __syncthreads();
    for (int d = 1; d < 1024; d <<= 1){
        int add = (t >= d) ? part[t-d] : 0;
        __syncthreads();
        part[t] += add;
        __syncthreads();
    }
    int run = part[t] - s;        // exclusive
    for (int i = 0; i < 108; ++i){
        st[base+i] = run;
        of[base+i] = run;
        run += c[base+i];
    }
    if (t == 1023) st[G3] = NN;   // sentinel end
}

// K2d: scatter points into cell-sorted order
__global__ __launch_bounds__(256) void k_scatter(const float4* __restrict__ w1, const float4* __restrict__ w2,
                                                 const unsigned* __restrict__ bmin, const unsigned* __restrict__ bmax,
                                                 int* __restrict__ offsets,
                                                 float4* __restrict__ sortedA, int* __restrict__ sortedIdx){
    int t = blockIdx.x*256 + threadIdx.x;     // 2*BN
    int cloud = (t >= BN) ? 1 : 0;
    int i = cloud ? t - BN : t;
    float4 p = (cloud ? w2 : w1)[i];
    int b = i >> 13;
    int seg = cloud*4 + b;
    int cx, cy, cz;
    cell_of(p.x, p.y, p.z, bmin, bmax, seg, cx, cy, cz);
    int pos = atomicAdd(&offsets[seg*G3P + (cz*G + cy)*G + cx], 1);
    int dst = cloud*BN + b*NN + pos;
    sortedA[dst] = p;                         // (x,y,z,|p|^2)
    sortedIdx[dst] = i & (NN-1);              // within-batch index
}

#define KSWAP(x,y) { unsigned long long _lo=(x), _hi=(y); bool _sw=_hi<_lo; (y)=_sw?_lo:_hi; (x)=_sw?_hi:_lo; }
#define INSERT_KEY(key)                                                     \
    if ((key) < A15){                                                       \
        A15 = (key);                                                        \
        KSWAP(A14,A15) KSWAP(A13,A14) KSWAP(A12,A13) KSWAP(A11,A12)         \
        KSWAP(A10,A11) KSWAP(A9,A10)  KSWAP(A8,A9)   KSWAP(A7,A8)           \
        KSWAP(A6,A7)   KSWAP(A5,A6)   KSWAP(A4,A5)   KSWAP(A3,A4)           \
        KSWAP(A2,A3)   KSWAP(A1,A2)   KSWAP(A0,A1)                          \
    }

// K2e: grid 16-NN. thread = query (cloud-1 points, processed in cell-sorted
// order for wave coherence). Expanding Chebyshev shells; rows of cells are
// contiguous cid runs -> contiguous sorted-array spans. Exactness: shell r
// lower bound (r-1)*hmin on any unexamined point; loop stops only when
// bound^2 (with conservative slack) exceeds current f64 16th distance, and
// every accepted candidate is f64-verified into the packed-key ladder.
__global__ __launch_bounds__(256) void k_knng(const float4* __restrict__ sortedA, const int* __restrict__ sortedIdx,
                                              const int* __restrict__ starts,
                                              const unsigned* __restrict__ bmin, const unsigned* __restrict__ bmax,
                                              int* __restrict__ outA, int* __restrict__ outB){
    int sp = blockIdx.x*256 + threadIdx.x;        // sorted position in cloud1 [0,BN)
    int candCloud = (blockIdx.y == 0) ? 1 : 0;    // y0: idx12 (cands=cloud2), y1: idx11 (cands=cloud1)
    int* out = (blockIdx.y == 0) ? outA : outB;
    int b = sp >> 13;
    float4 q = sortedA[sp];                       // cloud1 segment is at base 0
    int qorig = sortedIdx[sp];
    int seg = candCloud*4 + b;

    const float4* cA = sortedA + candCloud*BN + b*NN;
    const int*    cI = sortedIdx + candCloud*BN + b*NN;
    const int*    st = starts + (size_t)seg*G3P;

    int s3 = seg*3;
    float mnx = unmono_f32(bmin[s3+0]), mny = unmono_f32(bmin[s3+1]), mnz = unmono_f32(bmin[s3+2]);
    float mxx = unmono_f32(bmax[s3+0]), mxy = unmono_f32(bmax[s3+1]), mxz = unmono_f32(bmax[s3+2]);
    float hx = (mxx-mnx)*(1.f/G), hy = (mxy-mny)*(1.f/G), hz = (mxz-mnz)*(1.f/G);
    float hmin = fminf(hx, fminf(hy, hz));
    int cx, cy, cz;
    cell_of(q.x, q.y, q.z, bmin, bmax, seg, cx, cy, cz);

    float n2x = -2.f*q.x, n2y = -2.f*q.y, n2z = -2.f*q.z;
    float qq32 = q.w;
    double qx = q.x, qy = q.y, qz = q.z;
    double qq = fma(qx,qx, fma(qy,qy, qz*qz));

    const unsigned long long KINIT = 0xFFF0000000000000ull | 8191ull;
    unsigned long long A0=KINIT, A1=KINIT, A2=KINIT, A3=KINIT,
                       A4=KINIT, A5=KINIT, A6=KINIT, A7=KINIT,
                       A8=KINIT, A9=KINIT, A10=KINIT, A11=KINIT,
                       A12=KINIT, A13=KINIT, A14=KINIT, A15=KINIT;
    float d16a = __builtin_inff();                // current 16th distance^2 (f32 view)
    float thr  = __builtin_inff();                // screen threshold in t = d2-qq space

    #define SCAN_RUN(c0, c1)                                                     \
        { int _j0 = st[c0], _j1 = st[(c1)+1];                                    \
          for (int j = _j0; j < _j1; ++j){                                       \
              float4 cpt = cA[j];                                                \
              float t = fmaf(n2x, cpt.x, cpt.w);                                 \
              t = fmaf(n2y, cpt.y, t);                                           \
              t = fmaf(n2z, cpt.z, t);                                           \
              if (t < thr){                                                      \
                  double px = cpt.x, py = cpt.y, pz = cpt.z;                     \
                  double pp  = fma(px,px, fma(py,py, pz*pz));                    \
                  double dot = fma(qx,px, fma(qy,py, qz*pz));                    \
                  double d2 = qq + pp - 2.0*dot;                                 \
                  unsigned long long key = (mono_f64(d2) & ~8191ull)             \
                                         | (unsigned long long)(unsigned)cI[j];  \
                  INSERT_KEY(key)                                                \
                  d16a = fminf(d16a, (float)unmono_f64(A15));                    \
                  thr  = d16a - qq32 + 1e-4f;                                    \
              }                                                                  \
          }                                                                      \
        }

    for (int r = 0; r < G; ++r){
        if (r >= 1){
            float lb = (float)(r-1) * hmin;
            if (lb*lb*0.9998f - 1e-5f > d16a) break;   // conservative slack
        }
        for (int dz = -r; dz <= r; ++dz){
            int z = cz + dz; if ((unsigned)z >= (unsigned)G) continue;
            for (int dy = -r; dy <= r; ++dy){
                int y = cy + dy; if ((unsigned)y >= (unsigned)G) continue;
                int rowbase = (z*G + y)*G;
                bool edge = (dz == -r) || (dz == r) || (dy == -r) || (dy == r);
                if (edge){
                    int x0 = cx - r; if (x0 < 0) x0 = 0;
                    int x1 = cx + r; if (x1 > G-1) x1 = G-1;
                    SCAN_RUN(rowbase + x0, rowbase + x1)
                } else {
                    int xl = cx - r, xr = cx + r;
                    if (xl >= 0)   SCAN_RUN(rowbase + xl, rowbase + xl)
                    if (xr <= G-1) SCAN_RUN(rowbase + xr, rowbase + xr)
                }
            }
        }
    }

    int4* o = (int4*)(out + ((size_t)(b*NN + qorig))*16);
    o[0] = make_int4((int)(A0 & 8191ull),  (int)(A1 & 8191ull),
                     (int)(A2 & 8191ull),  (int)(A3 & 8191ull));
    o[1] = make_int4((int)(A4 & 8191ull),  (int)(A5 & 8191ull),
                     (int)(A6 & 8191ull),  (int)(A7 & 8191ull));
    o[2] = make_int4((int)(A8 & 8191ull),  (int)(A9 & 8191ull),
                     (int)(A10 & 8191ull), (int)(A11 & 8191ull));
    o[3] = make_int4((int)(A12 & 8191ull), (int)(A13 & 8191ull),
                     (int)(A14 & 8191ull), (int)(A15 & 8191ull));
}

// ---------------- K3: small MLP hidden states H[b,n,k,8] ----------------
__global__ __launch_bounds__(256) void k_h2(const float4* __restrict__ qpts, const float4* __restrict__ cpts,
                                            const int* __restrict__ idx,
                                            const float* __restrict__ w1, const float* __restrict__ b1,
                                            const float* __restrict__ w2, const float* __restrict__ b2,
                                            float* __restrict__ H){
    int i = blockIdx.x*256 + threadIdx.x;   // over BNK
    int gq = i >> 4;
    int b = gq >> 13;
    int m = idx[i];
    float4 p = cpts[b*NN + m];
    float4 q = qpts[gq];
    float x = p.x - q.x, y = p.y - q.y, z = p.z - q.z;
    float h1[8], h2[8];
    #pragma unroll
    for (int j = 0; j < 8; ++j){
        float v = b1[j] + w1[j*3+0]*x + w1[j*3+1]*y + w1[j*3+2]*z;
        h1[j] = fmaxf(v, 0.f);
    }
    #pragma unroll
    for (int j = 0; j < 8; ++j){
        float v = b2[j];
        #pragma unroll
        for (int jj = 0; jj < 8; ++jj) v = fmaf(w2[j*8+jj], h1[jj], v);
        h2[j] = fmaxf(v, 0.f);
    }
    float4* o = (float4*)(H + (size_t)i*8);
    o[0] = make_float4(h2[0],h2[1],h2[2],h2[3]);
    o[1] = make_float4(h2[4],h2[5],h2[6],h2[7]);
}

__device__ __forceinline__ float rl_f(int hb, int lane_c){
    return __int_as_float(__builtin_amdgcn_readlane(hb, lane_c));
}

// ---------------- K4: fused stage 1 -> p2n[b,n,co] ----------------
__global__ __launch_bounds__(256) void k_stage1(const float* __restrict__ A1, const float* __restrict__ A2,
                                                const int* __restrict__ idx12, const float* __restrict__ H12,
                                                const float4* __restrict__ xyzw1, const float4* __restrict__ xyzw2,
                                                const float* __restrict__ W1full, const float* __restrict__ W2,
                                                const float* __restrict__ b2, const float* __restrict__ w3,
                                                const float* __restrict__ b3, float* __restrict__ p2n){
    int lane = threadIdx.x & 63;
    int wv = threadIdx.x >> 6;
    int wgid = blockIdx.x*4 + wv;

    float w2r[64];
    const float4* w2p = (const float4*)(W2 + (size_t)lane*64);
    #pragma unroll
    for (int c4 = 0; c4 < 16; ++c4){
        float4 v = w2p[c4];
        w2r[c4*4+0]=v.x; w2r[c4*4+1]=v.y; w2r[c4*4+2]=v.z; w2r[c4*4+3]=v.w;
    }
    float w1cx = W1full[lane*131+128], w1cy = W1full[lane*131+129], w1cz = W1full[lane*131+130];
    float b2v = b2[lane], b3v = b3[lane];
    float w3r[8];
    {
        const float4* w3p = (const float4*)(w3 + (size_t)lane*8);
        float4 a = w3p[0], bq = w3p[1];
        w3r[0]=a.x; w3r[1]=a.y; w3r[2]=a.z; w3r[3]=a.w;
        w3r[4]=bq.x; w3r[5]=bq.y; w3r[6]=bq.z; w3r[7]=bq.w;
    }

    for (int task = wgid; task < BN; task += 4096){
        int b = task >> 13;
        float4 q = xyzw1[task];
        float a1 = A1[(size_t)task*64 + lane];
        float acc = 0.f;
        const int* ip = idx12 + (size_t)task*16;
        for (int k = 0; k < 16; ++k){
            int m = ip[k];
            float4 p = xyzw2[b*NN + m];
            float a2 = A2[(size_t)(b*NN+m)*64 + lane];
            float h = a1 + a2;
            h = fmaf(w1cx, p.x - q.x, h);
            h = fmaf(w1cy, p.y - q.y, h);
            h = fmaf(w1cz, p.z - q.z, h);
            h = fmaxf(h, 0.1f*h);                 // leaky relu
            int hb = __float_as_int(h);
            float c20 = 0.f, c21 = 0.f, c22 = 0.f, c23 = 0.f;
            #pragma unroll
            for (int c = 0; c < 64; c += 4){
                c20 = fmaf(w2r[c+0], rl_f(hb, c+0), c20);
                c21 = fmaf(w2r[c+1], rl_f(hb, c+1), c21);
                c22 = fmaf(w2r[c+2], rl_f(hb, c+2), c22);
                c23 = fmaf(w2r[c+3], rl_f(hb, c+3), c23);
            }
            float c2 = ((c20 + c21) + (c22 + c23)) + b2v;
            c2 = fmaxf(c2, 0.1f*c2);              // leaky relu
            const float4* hw = (const float4*)(H12 + (size_t)(task*16+k)*8);
            float4 ha = hw[0], hb2 = hw[1];
            float w = b3v;
            w = fmaf(w3r[0], ha.x, w); w = fmaf(w3r[1], ha.y, w);
            w = fmaf(w3r[2], ha.z, w); w = fmaf(w3r[3], ha.w, w);
            w = fmaf(w3r[4], hb2.x, w); w = fmaf(w3r[5], hb2.y, w);
            w = fmaf(w3r[6], hb2.z, w); w = fmaf(w3r[7], hb2.w, w);
            w = fmaxf(w, 0.f);                    // relu
            acc = fmaf(w, c2, acc);
        }
        p2n[(size_t)task*64 + lane] = acc;
    }
}

// ---------------- K5: fused stage 2 -> out[b,co,n] ----------------
__global__ __launch_bounds__(256) void k_stage2(const float* __restrict__ p2n, const int* __restrict__ idx11,
                                                const float* __restrict__ H11, const float* __restrict__ w3,
                                                const float* __restrict__ b3, float* __restrict__ out){
    __shared__ float tl[64*65];
    int lane = threadIdx.x & 63;
    int wv = threadIdx.x >> 6;
    int base = blockIdx.x*64;     // flat (b,n)
    int b = base >> 13;

    float w3r[8];
    {
        const float4* w3p = (const float4*)(w3 + (size_t)lane*8);
        float4 a = w3p[0], bq = w3p[1];
        w3r[0]=a.x; w3r[1]=a.y; w3r[2]=a.z; w3r[3]=a.w;
        w3r[4]=bq.x; w3r[5]=bq.y; w3r[6]=bq.z; w3r[7]=bq.w;
    }
    float b3v = b3[lane];

    for (int i = 0; i < 16; ++i){
        int col = base + wv*16 + i;
        const int* ip = idx11 + (size_t)col*16;
        const float* Hb = H11 + (size_t)col*16*8;
        float acc = 0.f;
        for (int k = 0; k < 16; ++k){
            int m = ip[k];
            float c = p2n[(size_t)(b*NN + m)*64 + lane];
            const float4* hw = (const float4*)(Hb + k*8);
            float4 ha = hw[0], hb2 = hw[1];
            float w = b3v;
            w = fmaf(w3r[0], ha.x, w);  w = fmaf(w3r[1], ha.y, w);
            w = fmaf(w3r[2], ha.z, w);  w = fmaf(w3r[3], ha.w, w);
            w = fmaf(w3r[4], hb2.x, w); w = fmaf(w3r[5], hb2.y, w);
            w = fmaf(w3r[6], hb2.z, w); w = fmaf(w3r[7], hb2.w, w);
            w = fmaxf(w, 0.f);
            acc = fmaf(w, c, acc);
        }
        tl[(wv*16+i)*65 + lane] = acc;
    }
    __syncthreads();
    int n0 = base & (NN-1);
    #pragma unroll
    for (int i = 0; i < 16; ++i){
        int co = i*4 + wv;
        float v = tl[lane*65 + co];
        out[((size_t)b*64 + co)*NN + n0 + lane] = v;
    }
}

extern "C" void kernel_launch(void* const* d_in, const int* in_sizes, int n_in,
                              void* d_out, int out_size, void* d_ws, size_t ws_size,
                              hipStream_t stream) {
    const float* xyz1   = (const float*)d_in[0];
    const float* feat1  = (const float*)d_in[1];
    const float* xyz2   = (const float*)d_in[2];
    const float* feat2  = (const float*)d_in[3];
    const float* cost_w1 = (const float*)d_in[4];
    const float* cost_b1 = (const float*)d_in[5];
    const float* cost_w2 = (const float*)d_in[6];
    const float* cost_b2 = (const float*)d_in[7];
    const float* wn1_w1 = (const float*)d_in[8];
    const float* wn1_b1 = (const float*)d_in[9];
    const float* wn1_w2 = (const float*)d_in[10];
    const float* wn1_b2 = (const float*)d_in[11];
    const float* wn1_w3 = (const float*)d_in[12];
    const float* wn1_b3 = (const float*)d_in[13];
    const float* wn2_w1 = (const float*)d_in[14];
    const float* wn2_b1 = (const float*)d_in[15];
    const float* wn2_w2 = (const float*)d_in[16];
    const float* wn2_b2 = (const float*)d_in[17];
    const float* wn2_w3 = (const float*)d_in[18];
    const float* wn2_b3 = (const float*)d_in[19];

    char* ws = (char*)d_ws;
    float4* xyzw1 = (float4*)(ws + 0);
    float4* xyzw2 = (float4*)(ws + 524288);
    float*  A1    = (float*)(ws + 1048576);
    float*  A2    = (float*)(ws + 9437184);
    int*    idx12 = (int*)  (ws + 17825792);
    int*    idx11 = (int*)  (ws + 19922944);
    float*  H12   = (float*)(ws + 22020096);
    float*  H11   = (float*)(ws + 38797312);
    float*  p2n   = (float*)(ws + 55574528);

    // grid structures overlaid on the H12 region (dead until k_h2 runs)
    char* g = ws + 22020096;
    int*      counts    = (int*)     (g + 0);          // 8*G3P*4 = 3539200
    int*      starts    = (int*)     (g + 3539200);    // 3539200
    int*      offsets   = (int*)     (g + 7078400);    // 3539200
    float4*   sortedA   = (float4*)  (g + 10617600);   // 2*BN*16 = 1048576
    int*      sortedIdx = (int*)     (g + 11666176);   // 2*BN*4  = 262144
    unsigned* bmin      = (unsigned*)(g + 11928320);   // 96
    unsigned* bmax      = (unsigned*)(g + 11928448);   // 96

    hipMemsetAsync(counts, 0, (size_t)8*G3P*4, stream);
    hipMemsetAsync(bmin, 0xFF, 96, stream);
    hipMemsetAsync(bmax, 0x00, 96, stream);

    k_xyzw<<<256, 256, 0, stream>>>(xyz1, xyz2, xyzw1, xyzw2);
    k_prefeat<<<512, 64, 0, stream>>>(feat1, cost_w1, cost_b1, 0,  A1);
    k_prefeat<<<512, 64, 0, stream>>>(feat2, cost_w1, nullptr, 64, A2);
    k_bounds<<<256, 256, 0, stream>>>(xyzw1, xyzw2, bmin, bmax);
    k_count<<<256, 256, 0, stream>>>(xyzw1, xyzw2, bmin, bmax, counts);
    k_scan<<<8, 1024, 0, stream>>>(counts, starts, offsets);
    k_scatter<<<256, 256, 0, stream>>>(xyzw1, xyzw2, bmin, bmax, offsets, sortedA, sortedIdx);
    k_knng<<<dim3(128, 2), 256, 0, stream>>>(sortedA, sortedIdx, starts, bmin, bmax, idx12, idx11);
    k_h2<<<2048, 256, 0, stream>>>(xyzw1, xyzw2, idx12, wn2_w1, wn2_b1, wn2_w2, wn2_b2, H12);
    k_h2<<<2048, 256, 0, stream>>>(xyzw1, xyzw1, idx11, wn1_w1, wn1_b1, wn1_w2, wn1_b2, H11);
    k_stage1<<<1024, 256, 0, stream>>>(A1, A2, idx12, H12, xyzw1, xyzw2,
                                       cost_w1, cost_w2, cost_b2, wn2_w3, wn2_b3, p2n);
    k_stage2<<<512, 256, 0, stream>>>(p2n, idx11, H11, wn1_w3, wn1_b3, (float*)d_out);
}

// Round 11
// 2606.909 us; speedup vs baseline: 1.1356x; 1.1356x over previous
//
#include <hip/hip_runtime.h>
#include <stdint.h>

#define BB 4
#define NN 8192
#define KK 16
#define BN (BB*NN)        // 32768
#define BNK (BN*KK)       // 524288

#define G   48
#define G3  (G*G*G)       // 110592
#define G3P (G3+8)        // padded; starts[G3] = NN sentinel

// ---------------- K0: pack xyz -> (x,y,z,|p|^2) float4 ----------------
__global__ void k_xyzw(const float* __restrict__ xyz1, const float* __restrict__ xyz2,
                       float4* __restrict__ w1, float4* __restrict__ w2){
    int t = blockIdx.x*256 + threadIdx.x;
    if (t >= 2*BN) return;
    const float* src; float4* dst; int i;
    if (t < BN){ src = xyz1; dst = w1; i = t; }
    else       { src = xyz2; dst = w2; i = t - BN; }
    int b = i >> 13, m = i & (NN-1);
    const float* p = src + (size_t)b*3*NN + m;
    float x = p[0], y = p[NN], z = p[2*NN];
    dst[i] = make_float4(x, y, z, x*x + y*y + z*z);
}

// ------------- K1: A[b,n,co] = bias[co] + sum_ci W1[co][colOff+ci]*feat[b,ci,n] -------------
__global__ __launch_bounds__(64) void k_prefeat(const float* __restrict__ feat,
                                                const float* __restrict__ W1,
                                                const float* __restrict__ bias, int colOff,
                                                float* __restrict__ out){
    __shared__ float Wt[64*64];   // [ci][co]
    __shared__ float bsh[64];
    int t = threadIdx.x;
    for (int ci = 0; ci < 64; ++ci)
        Wt[ci*64 + t] = W1[t*131 + colOff + ci];   // thread t = row co
    bsh[t] = bias ? bias[t] : 0.0f;
    __syncthreads();

    int col = blockIdx.x*64 + t;       // (b,n) flat
    int b = col >> 13, n = col & (NN-1);
    const float* f = feat + (size_t)b*64*NN + n;
    float acc[64];
    #pragma unroll
    for (int co = 0; co < 64; ++co) acc[co] = 0.f;
    for (int ci = 0; ci < 64; ++ci){
        float v = f[(size_t)ci*NN];
        const float4* wrow = (const float4*)(Wt + ci*64);
        #pragma unroll
        for (int c4 = 0; c4 < 16; ++c4){
            float4 w = wrow[c4];
            acc[c4*4+0] = fmaf(w.x, v, acc[c4*4+0]);
            acc[c4*4+1] = fmaf(w.y, v, acc[c4*4+1]);
            acc[c4*4+2] = fmaf(w.z, v, acc[c4*4+2]);
            acc[c4*4+3] = fmaf(w.w, v, acc[c4*4+3]);
        }
    }
    float4* o = (float4*)(out + (size_t)col*64);
    const float4* bs = (const float4*)bsh;
    #pragma unroll
    for (int c4 = 0; c4 < 16; ++c4){
        float4 bb = bs[c4];
        o[c4] = make_float4(acc[c4*4+0]+bb.x, acc[c4*4+1]+bb.y,
                            acc[c4*4+2]+bb.z, acc[c4*4+3]+bb.w);
    }
}

// ================= grid prep (cell-sort both clouds) =================
__device__ __forceinline__ unsigned mono_f32(float f){
    unsigned u = __float_as_uint(f);
    return ((int)u >= 0) ? (u | 0x80000000u) : ~u;
}
__device__ __forceinline__ float unmono_f32(unsigned v){
    unsigned u = ((int)v < 0) ? (v & 0x7FFFFFFFu) : ~v;
    return __uint_as_float(u);
}
__device__ __forceinline__ unsigned long long mono_f64(double d){
    unsigned long long u = (unsigned long long)__double_as_longlong(d);
    return ((long long)u >= 0) ? (u | 0x8000000000000000ull) : ~u;
}
__device__ __forceinline__ double unmono_f64(unsigned long long v){
    unsigned long long u = ((long long)v < 0) ? (v & 0x7FFFFFFFFFFFFFFFull) : ~v;
    return __longlong_as_double((long long)u);
}

__device__ __forceinline__ void cell_of(float x, float y, float z,
                                        const unsigned* bmin, const unsigned* bmax, int seg,
                                        int& cx, int& cy, int& cz){
    int s3 = seg*3;
    float mnx = unmono_f32(bmin[s3+0]), mny = unmono_f32(bmin[s3+1]), mnz = unmono_f32(bmin[s3+2]);
    float mxx = unmono_f32(bmax[s3+0]), mxy = unmono_f32(bmax[s3+1]), mxz = unmono_f32(bmax[s3+2]);
    float ivx = (float)G/(mxx-mnx), ivy = (float)G/(mxy-mny), ivz = (float)G/(mxz-mnz);
    cx = (int)((x-mnx)*ivx); cx = cx < 0 ? 0 : (cx > G-1 ? G-1 : cx);
    cy = (int)((y-mny)*ivy); cy = cy < 0 ? 0 : (cy > G-1 ? G-1 : cy);
    cz = (int)((z-mnz)*ivz); cz = cz < 0 ? 0 : (cz > G-1 ? G-1 : cz);
}

__global__ __launch_bounds__(256) void k_bounds(const float4* __restrict__ w1, const float4* __restrict__ w2,
                                                unsigned* __restrict__ bmin, unsigned* __restrict__ bmax){
    int t = blockIdx.x*256 + threadIdx.x;     // 2*BN
    int cloud = (t >= BN) ? 1 : 0;
    int i = cloud ? t - BN : t;
    float4 p = (cloud ? w2 : w1)[i];
    float mn0 = p.x, mn1 = p.y, mn2 = p.z;
    float mx0 = p.x, mx1 = p.y, mx2 = p.z;
    #pragma unroll
    for (int d = 1; d < 64; d <<= 1){
        mn0 = fminf(mn0, __shfl_xor(mn0, d)); mx0 = fmaxf(mx0, __shfl_xor(mx0, d));
        mn1 = fminf(mn1, __shfl_xor(mn1, d)); mx1 = fmaxf(mx1, __shfl_xor(mx1, d));
        mn2 = fminf(mn2, __shfl_xor(mn2, d)); mx2 = fmaxf(mx2, __shfl_xor(mx2, d));
    }
    if ((threadIdx.x & 63) == 0){
        int seg = cloud*4 + (i >> 13), s3 = seg*3;
        atomicMin(&bmin[s3+0], mono_f32(mn0)); atomicMax(&bmax[s3+0], mono_f32(mx0));
        atomicMin(&bmin[s3+1], mono_f32(mn1)); atomicMax(&bmax[s3+1], mono_f32(mx1));
        atomicMin(&bmin[s3+2], mono_f32(mn2)); atomicMax(&bmax[s3+2], mono_f32(mx2));
    }
}

__global__ __launch_bounds__(256) void k_count(const float4* __restrict__ w1, const float4* __restrict__ w2,
                                               const unsigned* __restrict__ bmin, const unsigned* __restrict__ bmax,
                                               int* __restrict__ counts){
    int t = blockIdx.x*256 + threadIdx.x;     // 2*BN
    int cloud = (t >= BN) ? 1 : 0;
    int i = cloud ? t - BN : t;
    float4 p = (cloud ? w2 : w1)[i];
    int seg = cloud*4 + (i >> 13);
    int cx, cy, cz;
    cell_of(p.x, p.y, p.z, bmin, bmax, seg, cx, cy, cz);
    atomicAdd(&counts[seg*G3P + (cz*G + cy)*G + cx], 1);
}

__global__ __launch_bounds__(1024) void k_scan(const int* __restrict__ counts,
                                               int* __restrict__ starts, int* __restrict__ offsets){
    __shared__ int part[1024];
    int seg = blockIdx.x;
    const int* c = counts + (size_t)seg*G3P;
    int* st = starts + (size_t)seg*G3P;
    int* of = offsets + (size_t)seg*G3P;
    int t = threadIdx.x;
    int base = t*108;
    int s = 0;
    for (int i = 0; i < 108; ++i) s += c[base+i];
    part[t] = s;
    __syncthreads();
    for (int d = 1; d < 1024; d <<= 1){
        int add = (t >= d) ? part[t-d] : 0;
        __syncthreads();
        part[t] += add;
        __syncthreads();
    }
    int run = part[t] - s;        // exclusive
    for (int i = 0; i < 108; ++i){
        st[base+i] = run;
        of[base+i] = run;
        run += c[base+i];
    }
    if (t == 1023) st[G3] = NN;   // sentinel end
}

__global__ __launch_bounds__(256) void k_scatter(const float4* __restrict__ w1, const float4* __restrict__ w2,
                                                 const unsigned* __restrict__ bmin, const unsigned* __restrict__ bmax,
                                                 int* __restrict__ offsets,
                                                 float4* __restrict__ sortedA, int* __restrict__ sortedIdx){
    int t = blockIdx.x*256 + threadIdx.x;     // 2*BN
    int cloud = (t >= BN) ? 1 : 0;
    int i = cloud ? t - BN : t;
    float4 p = (cloud ? w2 : w1)[i];
    int b = i >> 13;
    int seg = cloud*4 + b;
    int cx, cy, cz;
    cell_of(p.x, p.y, p.z, bmin, bmax, seg, cx, cy, cz);
    int pos = atomicAdd(&offsets[seg*G3P + (cz*G + cy)*G + cx], 1);
    int dst = cloud*BN + b*NN + pos;
    sortedA[dst] = p;                         // (x,y,z,|p|^2)
    sortedIdx[dst] = i & (NN-1);              // within-batch index
}

// ================= K2: exact 16-NN, block-windowed (round-8 machinery) =================
// Block = 64 consecutive CELL-SORTED queries (spatially tight). 8 waves scan
// Chebyshev shells of cells around the block's query-cell box, rows assigned
// round-robin (counter%8==wv). Screening = round-8 exact machinery: f32
// screen -> LDS stack -> f64 verify into packed-u64 register ladder; shared
// per-query threshold via LDS atomicMin; 8-way tree merge at the end.
// Exactness: wave stops at shell r only when ((r-1)*hmin)^2 (with slack)
// exceeds min(own d16, shared d16 estimate); shared estimate >= merged 16th,
// so every skipped cell is provably outside the merged top-16. Loop capped
// at 3G shells -> worst case scans the whole grid -> exact regardless.
#define SCAP 19

#define KSWAP(x,y) { unsigned long long _lo=(x), _hi=(y); bool _sw=_hi<_lo; (y)=_sw?_lo:_hi; (x)=_sw?_hi:_lo; }
#define INSERT_KEY(key)                                                     \
    if ((key) < A15){                                                       \
        A15 = (key);                                                        \
        KSWAP(A14,A15) KSWAP(A13,A14) KSWAP(A12,A13) KSWAP(A11,A12)         \
        KSWAP(A10,A11) KSWAP(A9,A10)  KSWAP(A8,A9)   KSWAP(A7,A8)           \
        KSWAP(A6,A7)   KSWAP(A5,A6)   KSWAP(A4,A5)   KSWAP(A3,A4)           \
        KSWAP(A2,A3)   KSWAP(A1,A2)   KSWAP(A0,A1)                          \
    }

#define FLUSHW()                                                             \
    do {                                                                     \
        for (int s = 0; s < cnt; ++s){                                       \
            int j = stk[s];                                                  \
            float4 c = cb[j];                                                \
            double px = c.x, py = c.y, pz = c.z;                             \
            double pp  = fma(px,px, fma(py,py, pz*pz));                      \
            double dot = fma(qx,px, fma(qy,py, qz*pz));                      \
            double d2 = qq + pp - 2.0*dot;                                   \
            unsigned long long key = (mono_f64(d2) & ~8191ull)               \
                                   | (unsigned long long)(unsigned)cI[j];    \
            INSERT_KEY(key)                                                  \
        }                                                                    \
        cnt = 0;                                                             \
        d16a = (float)unmono_f64(A15);                                       \
        unsigned m = mono_f32(d16a - qq32);                                  \
        unsigned old = atomicMin(&thrsh[lane], m);                           \
        bdt = unmono_f32(old < m ? old : m) + 1e-4f;                         \
    } while(0)

#define PUSH_RUN(c0,c1)                                                      \
    { int _j0 = st[(c0)], _j1 = st[(c1)+1];                                  \
      for (int j = _j0; j < _j1; ++j){                                       \
          float4 c = cb[j];                                                  \
          float t = fmaf(n2x, c.x, c.w);                                     \
          t = fmaf(n2y, c.y, t);                                             \
          t = fmaf(n2z, c.z, t);                                             \
          if (t < bdt){ stk[cnt] = j; cnt++; }                               \
          if (++chk >= 4){ chk = 0; if (__any(cnt >= 16)) FLUSHW(); }        \
      }                                                                      \
    }

__device__ __forceinline__ int wred_min(int v){
    #pragma unroll
    for (int d = 1; d < 64; d <<= 1) v = min(v, __shfl_xor(v, d));
    return __builtin_amdgcn_readfirstlane(v);
}
__device__ __forceinline__ int wred_max(int v){
    #pragma unroll
    for (int d = 1; d < 64; d <<= 1) v = max(v, __shfl_xor(v, d));
    return __builtin_amdgcn_readfirstlane(v);
}

__global__ __launch_bounds__(512, 2) void k_knnw(const float4* __restrict__ sortedA,
                                                 const int* __restrict__ sortedIdx,
                                                 const int* __restrict__ starts,
                                                 const unsigned* __restrict__ bmin,
                                                 const unsigned* __restrict__ bmax,
                                                 int* __restrict__ outA, int* __restrict__ outB){
    __shared__ unsigned int thrsh[64];
    __shared__ __align__(16) char pool[38912];   // stacks (512*19*4) / merge (4*64*17*8)

    int tid = threadIdx.x;
    int lane = tid & 63;
    int wv = tid >> 6;
    int candCloud = (blockIdx.y == 0) ? 1 : 0;   // y0: idx12 (cands=cloud2), y1: idx11
    int* out = (blockIdx.y == 0) ? outA : outB;

    int sp = blockIdx.x*64 + lane;               // sorted query position (cloud1)
    int b = sp >> 13;                            // lane-expr (uniform value) -> vector loads
    float4 q = sortedA[sp];
    int qorig = sortedIdx[sp];
    const float4* cb = sortedA + candCloud*BN + b*NN;
    const int*    cI = sortedIdx + candCloud*BN + b*NN;

    int segs = __builtin_amdgcn_readfirstlane(candCloud*4 + b);   // SGPR -> scalar loads
    const int* st = starts + (size_t)segs*G3P;

    int s3 = segs*3;
    float mnxx = unmono_f32(bmin[s3+0]), mnyy = unmono_f32(bmin[s3+1]), mnzz = unmono_f32(bmin[s3+2]);
    float mxxx = unmono_f32(bmax[s3+0]), mxyy = unmono_f32(bmax[s3+1]), mxzz = unmono_f32(bmax[s3+2]);
    float hx = (mxxx-mnxx)*(1.f/G), hy = (mxyy-mnyy)*(1.f/G), hz = (mxzz-mnzz)*(1.f/G);
    float hmin = fminf(hx, fminf(hy, hz));

    int cx, cy, cz;
    cell_of(q.x, q.y, q.z, bmin, bmax, segs, cx, cy, cz);
    int bx0 = wred_min(cx), bx1 = wred_max(cx);
    int by0 = wred_min(cy), by1 = wred_max(cy);
    int bz0 = wred_min(cz), bz1 = wred_max(cz);

    float n2x = -2.f*q.x, n2y = -2.f*q.y, n2z = -2.f*q.z;
    float qq32 = q.w;
    double qx = q.x, qy = q.y, qz = q.z;
    double qq = fma(qx,qx, fma(qy,qy, qz*qz));

    if (tid < 64) thrsh[tid] = 0xFF800000u;      // mono(+inf)
    __syncthreads();

    const unsigned long long KINIT = 0xFFF0000000000000ull | 8191ull;
    unsigned long long A0=KINIT, A1=KINIT, A2=KINIT, A3=KINIT,
                       A4=KINIT, A5=KINIT, A6=KINIT, A7=KINIT,
                       A8=KINIT, A9=KINIT, A10=KINIT, A11=KINIT,
                       A12=KINIT, A13=KINIT, A14=KINIT, A15=KINIT;
    float d16a = __builtin_inff();
    float bdt  = __builtin_inff();
    int cnt = 0, chk = 0, rowctr = 0;
    int* stk = ((int*)pool) + tid*SCAP;

    for (int r = 0; r <= 3*G; ++r){
        if (r >= 1){
            if (__any(cnt >= 1)) FLUSHW();       // publish before stop decision
            float ts = unmono_f32(thrsh[lane]);
            bdt = fminf(bdt, ts + 1e-4f);
            float est = fminf(d16a, ts + qq32);  // >= merged 16th distance^2
            float lb = (float)(r-1) * hmin;
            if (__all(lb*lb*0.9998f - 1e-5f > est)) break;
        }
        int z0 = bz0 - r, z1 = bz1 + r;
        int y0 = by0 - r, y1 = by1 + r;
        int x0 = bx0 - r, x1 = bx1 + r;
        int zs = z0 < 0 ? 0 : z0, ze = z1 > G-1 ? G-1 : z1;
        int ys = y0 < 0 ? 0 : y0, ye = y1 > G-1 ? G-1 : y1;
        int xs = x0 < 0 ? 0 : x0, xe = x1 > G-1 ? G-1 : x1;
        for (int z = zs; z <= ze; ++z){
            bool zedge = (z == z0) || (z == z1);
            for (int y = ys; y <= ye; ++y){
                bool full = (r == 0) || zedge || (y == y0) || (y == y1);
                int rowbase = (z*G + y)*G;
                if ((rowctr++ & 7) != wv) continue;
                if (full){
                    PUSH_RUN(rowbase + xs, rowbase + xe)
                } else {
                    if (x0 >= 0)   PUSH_RUN(rowbase + x0, rowbase + x0)
                    if (x1 <= G-1) PUSH_RUN(rowbase + x1, rowbase + x1)
                }
            }
        }
    }
    FLUSHW();

    __syncthreads();                             // stacks dead; pool becomes merge area
    unsigned long long* mrg = (unsigned long long*)pool;   // [4][64][17]
    #pragma unroll
    for (int r = 4; r >= 1; r >>= 1){
        if (wv >= r && wv < 2*r){
            unsigned long long* dst = mrg + ((size_t)(wv - r)*64 + lane)*17;
            dst[0]=A0;  dst[1]=A1;  dst[2]=A2;  dst[3]=A3;
            dst[4]=A4;  dst[5]=A5;  dst[6]=A6;  dst[7]=A7;
            dst[8]=A8;  dst[9]=A9;  dst[10]=A10; dst[11]=A11;
            dst[12]=A12; dst[13]=A13; dst[14]=A14; dst[15]=A15;
        }
        __syncthreads();
        if (wv < r){
            const unsigned long long* src = mrg + ((size_t)wv*64 + lane)*17;
            for (int i = 0; i < 16; ++i){
                unsigned long long bkey = src[i];
                if (__all(bkey >= A15)) break;       // uniform early-out
                INSERT_KEY(bkey)
            }
        }
        __syncthreads();
    }
    if (wv == 0){
        int4* o = (int4*)(out + ((size_t)(b*NN + qorig))*16);
        o[0] = make_int4((int)(A0 & 8191ull),  (int)(A1 & 8191ull),
                         (int)(A2 & 8191ull),  (int)(A3 & 8191ull));
        o[1] = make_int4((int)(A4 & 8191ull),  (int)(A5 & 8191ull),
                         (int)(A6 & 8191ull),  (int)(A7 & 8191ull));
        o[2] = make_int4((int)(A8 & 8191ull),  (int)(A9 & 8191ull),
                         (int)(A10 & 8191ull), (int)(A11 & 8191ull));
        o[3] = make_int4((int)(A12 & 8191ull), (int)(A13 & 8191ull),
                         (int)(A14 & 8191ull), (int)(A15 & 8191ull));
    }
}

// ---------------- K3: small MLP hidden states H[b,n,k,8] ----------------
__global__ __launch_bounds__(256) void k_h2(const float4* __restrict__ qpts, const float4* __restrict__ cpts,
                                            const int* __restrict__ idx,
                                            const float* __restrict__ w1, const float* __restrict__ b1,
                                            const float* __restrict__ w2, const float* __restrict__ b2,
                                            float* __restrict__ H){
    int i = blockIdx.x*256 + threadIdx.x;   // over BNK
    int gq = i >> 4;
    int b = gq >> 13;
    int m = idx[i];
    float4 p = cpts[b*NN + m];
    float4 q = qpts[gq];
    float x = p.x - q.x, y = p.y - q.y, z = p.z - q.z;
    float h1[8], h2[8];
    #pragma unroll
    for (int j = 0; j < 8; ++j){
        float v = b1[j] + w1[j*3+0]*x + w1[j*3+1]*y + w1[j*3+2]*z;
        h1[j] = fmaxf(v, 0.f);
    }
    #pragma unroll
    for (int j = 0; j < 8; ++j){
        float v = b2[j];
        #pragma unroll
        for (int jj = 0; jj < 8; ++jj) v = fmaf(w2[j*8+jj], h1[jj], v);
        h2[j] = fmaxf(v, 0.f);
    }
    float4* o = (float4*)(H + (size_t)i*8);
    o[0] = make_float4(h2[0],h2[1],h2[2],h2[3]);
    o[1] = make_float4(h2[4],h2[5],h2[6],h2[7]);
}

__device__ __forceinline__ float rl_f(int hb, int lane_c){
    return __int_as_float(__builtin_amdgcn_readlane(hb, lane_c));
}

// ---------------- K4: fused stage 1 -> p2n[b,n,co] ----------------
__global__ __launch_bounds__(256) void k_stage1(const float* __restrict__ A1, const float* __restrict__ A2,
                                                const int* __restrict__ idx12, const float* __restrict__ H12,
                                                const float4* __restrict__ xyzw1, const float4* __restrict__ xyzw2,
                                                const float* __restrict__ W1full, const float* __restrict__ W2,
                                                const float* __restrict__ b2, const float* __restrict__ w3,
                                                const float* __restrict__ b3, float* __restrict__ p2n){
    int lane = threadIdx.x & 63;
    int wv = threadIdx.x >> 6;
    int wgid = blockIdx.x*4 + wv;

    float w2r[64];
    const float4* w2p = (const float4*)(W2 + (size_t)lane*64);
    #pragma unroll
    for (int c4 = 0; c4 < 16; ++c4){
        float4 v = w2p[c4];
        w2r[c4*4+0]=v.x; w2r[c4*4+1]=v.y; w2r[c4*4+2]=v.z; w2r[c4*4+3]=v.w;
    }
    float w1cx = W1full[lane*131+128], w1cy = W1full[lane*131+129], w1cz = W1full[lane*131+130];
    float b2v = b2[lane], b3v = b3[lane];
    float w3r[8];
    {
        const float4* w3p = (const float4*)(w3 + (size_t)lane*8);
        float4 a = w3p[0], bq = w3p[1];
        w3r[0]=a.x; w3r[1]=a.y; w3r[2]=a.z; w3r[3]=a.w;
        w3r[4]=bq.x; w3r[5]=bq.y; w3r[6]=bq.z; w3r[7]=bq.w;
    }

    for (int task = wgid; task < BN; task += 4096){
        int b = task >> 13;
        float4 q = xyzw1[task];
        float a1 = A1[(size_t)task*64 + lane];
        float acc = 0.f;
        const int* ip = idx12 + (size_t)task*16;
        for (int k = 0; k < 16; ++k){
            int m = ip[k];
            float4 p = xyzw2[b*NN + m];
            float a2 = A2[(size_t)(b*NN+m)*64 + lane];
            float h = a1 + a2;
            h = fmaf(w1cx, p.x - q.x, h);
            h = fmaf(w1cy, p.y - q.y, h);
            h = fmaf(w1cz, p.z - q.z, h);
            h = fmaxf(h, 0.1f*h);                 // leaky relu
            int hb = __float_as_int(h);
            float c20 = 0.f, c21 = 0.f, c22 = 0.f, c23 = 0.f;
            #pragma unroll
            for (int c = 0; c < 64; c += 4){
                c20 = fmaf(w2r[c+0], rl_f(hb, c+0), c20);
                c21 = fmaf(w2r[c+1], rl_f(hb, c+1), c21);
                c22 = fmaf(w2r[c+2], rl_f(hb, c+2), c22);
                c23 = fmaf(w2r[c+3], rl_f(hb, c+3), c23);
            }
            float c2 = ((c20 + c21) + (c22 + c23)) + b2v;
            c2 = fmaxf(c2, 0.1f*c2);              // leaky relu
            const float4* hw = (const float4*)(H12 + (size_t)(task*16+k)*8);
            float4 ha = hw[0], hb2 = hw[1];
            float w = b3v;
            w = fmaf(w3r[0], ha.x, w); w = fmaf(w3r[1], ha.y, w);
            w = fmaf(w3r[2], ha.z, w); w = fmaf(w3r[3], ha.w, w);
            w = fmaf(w3r[4], hb2.x, w); w = fmaf(w3r[5], hb2.y, w);
            w = fmaf(w3r[6], hb2.z, w); w = fmaf(w3r[7], hb2.w, w);
            w = fmaxf(w, 0.f);                    // relu
            acc = fmaf(w, c2, acc);
        }
        p2n[(size_t)task*64 + lane] = acc;
    }
}

// ---------------- K5: fused stage 2 -> out[b,co,n] ----------------
__global__ __launch_bounds__(256) void k_stage2(const float* __restrict__ p2n, const int* __restrict__ idx11,
                                                const float* __restrict__ H11, const float* __restrict__ w3,
                                                const float* __restrict__ b3, float* __restrict__ out){
    __shared__ float tl[64*65];
    int lane = threadIdx.x & 63;
    int wv = threadIdx.x >> 6;
    int base = blockIdx.x*64;     // flat (b,n)
    int b = base >> 13;

    float w3r[8];
    {
        const float4* w3p = (const float4*)(w3 + (size_t)lane*8);
        float4 a = w3p[0], bq = w3p[1];
        w3r[0]=a.x; w3r[1]=a.y; w3r[2]=a.z; w3r[3]=a.w;
        w3r[4]=bq.x; w3r[5]=bq.y; w3r[6]=bq.z; w3r[7]=bq.w;
    }
    float b3v = b3[lane];

    for (int i = 0; i < 16; ++i){
        int col = base + wv*16 + i;
        const int* ip = idx11 + (size_t)col*16;
        const float* Hb = H11 + (size_t)col*16*8;
        float acc = 0.f;
        for (int k = 0; k < 16; ++k){
            int m = ip[k];
            float c = p2n[(size_t)(b*NN + m)*64 + lane];
            const float4* hw = (const float4*)(Hb + k*8);
            float4 ha = hw[0], hb2 = hw[1];
            float w = b3v;
            w = fmaf(w3r[0], ha.x, w);  w = fmaf(w3r[1], ha.y, w);
            w = fmaf(w3r[2], ha.z, w);  w = fmaf(w3r[3], ha.w, w);
            w = fmaf(w3r[4], hb2.x, w); w = fmaf(w3r[5], hb2.y, w);
            w = fmaf(w3r[6], hb2.z, w); w = fmaf(w3r[7], hb2.w, w);
            w = fmaxf(w, 0.f);
            acc = fmaf(w, c, acc);
        }
        tl[(wv*16+i)*65 + lane] = acc;
    }
    __syncthreads();
    int n0 = base & (NN-1);
    #pragma unroll
    for (int i = 0; i < 16; ++i){
        int co = i*4 + wv;
        float v = tl[lane*65 + co];
        out[((size_t)b*64 + co)*NN + n0 + lane] = v;
    }
}

extern "C" void kernel_launch(void* const* d_in, const int* in_sizes, int n_in,
                              void* d_out, int out_size, void* d_ws, size_t ws_size,
                              hipStream_t stream) {
    const float* xyz1   = (const float*)d_in[0];
    const float* feat1  = (const float*)d_in[1];
    const float* xyz2   = (const float*)d_in[2];
    const float* feat2  = (const float*)d_in[3];
    const float* cost_w1 = (const float*)d_in[4];
    const float* cost_b1 = (const float*)d_in[5];
    const float* cost_w2 = (const float*)d_in[6];
    const float* cost_b2 = (const float*)d_in[7];
    const float* wn1_w1 = (const float*)d_in[8];
    const float* wn1_b1 = (const float*)d_in[9];
    const float* wn1_w2 = (const float*)d_in[10];
    const float* wn1_b2 = (const float*)d_in[11];
    const float* wn1_w3 = (const float*)d_in[12];
    const float* wn1_b3 = (const float*)d_in[13];
    const float* wn2_w1 = (const float*)d_in[14];
    const float* wn2_b1 = (const float*)d_in[15];
    const float* wn2_w2 = (const float*)d_in[16];
    const float* wn2_b2 = (const float*)d_in[17];
    const float* wn2_w3 = (const float*)d_in[18];
    const float* wn2_b3 = (const float*)d_in[19];

    char* ws = (char*)d_ws;
    float4* xyzw1 = (float4*)(ws + 0);
    float4* xyzw2 = (float4*)(ws + 524288);
    float*  A1    = (float*)(ws + 1048576);
    float*  A2    = (float*)(ws + 9437184);
    int*    idx12 = (int*)  (ws + 17825792);
    int*    idx11 = (int*)  (ws + 19922944);
    float*  H12   = (float*)(ws + 22020096);
    float*  H11   = (float*)(ws + 38797312);
    float*  p2n   = (float*)(ws + 55574528);

    // grid structures overlaid on the H12 region (dead until k_h2 runs)
    char* g = ws + 22020096;
    int*      counts    = (int*)     (g + 0);          // 8*G3P*4 = 3539200
    int*      starts    = (int*)     (g + 3539200);    // 3539200
    int*      offsets   = (int*)     (g + 7078400);    // 3539200
    float4*   sortedA   = (float4*)  (g + 10617600);   // 2*BN*16 = 1048576
    int*      sortedIdx = (int*)     (g + 11666176);   // 2*BN*4  = 262144
    unsigned* bmin      = (unsigned*)(g + 11928320);   // 96
    unsigned* bmax      = (unsigned*)(g + 11928448);   // 96

    hipMemsetAsync(counts, 0, (size_t)8*G3P*4, stream);
    hipMemsetAsync(bmin, 0xFF, 96, stream);
    hipMemsetAsync(bmax, 0x00, 96, stream);

    k_xyzw<<<256, 256, 0, stream>>>(xyz1, xyz2, xyzw1, xyzw2);
    k_prefeat<<<512, 64, 0, stream>>>(feat1, cost_w1, cost_b1, 0,  A1);
    k_prefeat<<<512, 64, 0, stream>>>(feat2, cost_w1, nullptr, 64, A2);
    k_bounds<<<256, 256, 0, stream>>>(xyzw1, xyzw2, bmin, bmax);
    k_count<<<256, 256, 0, stream>>>(xyzw1, xyzw2, bmin, bmax, counts);
    k_scan<<<8, 1024, 0, stream>>>(counts, starts, offsets);
    k_scatter<<<256, 256, 0, stream>>>(xyzw1, xyzw2, bmin, bmax, offsets, sortedA, sortedIdx);
    k_knnw<<<dim3(512, 2), 512, 0, stream>>>(sortedA, sortedIdx, starts, bmin, bmax, idx12, idx11);
    k_h2<<<2048, 256, 0, stream>>>(xyzw1, xyzw2, idx12, wn2_w1, wn2_b1, wn2_w2, wn2_b2, H12);
    k_h2<<<2048, 256, 0, stream>>>(xyzw1, xyzw1, idx11, wn1_w1, wn1_b1, wn1_w2, wn1_b2, H11);
    k_stage1<<<1024, 256, 0, stream>>>(A1, A2, idx12, H12, xyzw1, xyzw2,
                                       cost_w1, cost_w2, cost_b2, wn2_w3, wn2_b3, p2n);
    k_stage2<<<512, 256, 0, stream>>>(p2n, idx11, H11, wn1_w3, wn1_b3, (float*)d_out);
}

// Round 12
// 956.576 us; speedup vs baseline: 3.0949x; 2.7252x over previous
//
#include <hip/hip_runtime.h>
#include <stdint.h>

#define BB 4
#define NN 8192
#define KK 16
#define BN (BB*NN)        // 32768
#define BNK (BN*KK)       // 524288

#define NB  4096          // z-sort bins
#define NBP 4104          // padded; starts[NB] = NN sentinel
#define S   256           // candidate stripe size
#define SCAP 19

// ---------------- K0: pack xyz -> (x,y,z,|p|^2) float4 ----------------
__global__ void k_xyzw(const float* __restrict__ xyz1, const float* __restrict__ xyz2,
                       float4* __restrict__ w1, float4* __restrict__ w2){
    int t = blockIdx.x*256 + threadIdx.x;
    if (t >= 2*BN) return;
    const float* src; float4* dst; int i;
    if (t < BN){ src = xyz1; dst = w1; i = t; }
    else       { src = xyz2; dst = w2; i = t - BN; }
    int b = i >> 13, m = i & (NN-1);
    const float* p = src + (size_t)b*3*NN + m;
    float x = p[0], y = p[NN], z = p[2*NN];
    dst[i] = make_float4(x, y, z, x*x + y*y + z*z);
}

// ------------- K1: A[b,n,co] = bias[co] + sum_ci W1[co][colOff+ci]*feat[b,ci,n] -------------
__global__ __launch_bounds__(64) void k_prefeat(const float* __restrict__ feat,
                                                const float* __restrict__ W1,
                                                const float* __restrict__ bias, int colOff,
                                                float* __restrict__ out){
    __shared__ float Wt[64*64];   // [ci][co]
    __shared__ float bsh[64];
    int t = threadIdx.x;
    for (int ci = 0; ci < 64; ++ci)
        Wt[ci*64 + t] = W1[t*131 + colOff + ci];   // thread t = row co
    bsh[t] = bias ? bias[t] : 0.0f;
    __syncthreads();

    int col = blockIdx.x*64 + t;       // (b,n) flat
    int b = col >> 13, n = col & (NN-1);
    const float* f = feat + (size_t)b*64*NN + n;
    float acc[64];
    #pragma unroll
    for (int co = 0; co < 64; ++co) acc[co] = 0.f;
    for (int ci = 0; ci < 64; ++ci){
        float v = f[(size_t)ci*NN];
        const float4* wrow = (const float4*)(Wt + ci*64);
        #pragma unroll
        for (int c4 = 0; c4 < 16; ++c4){
            float4 w = wrow[c4];
            acc[c4*4+0] = fmaf(w.x, v, acc[c4*4+0]);
            acc[c4*4+1] = fmaf(w.y, v, acc[c4*4+1]);
            acc[c4*4+2] = fmaf(w.z, v, acc[c4*4+2]);
            acc[c4*4+3] = fmaf(w.w, v, acc[c4*4+3]);
        }
    }
    float4* o = (float4*)(out + (size_t)col*64);
    const float4* bs = (const float4*)bsh;
    #pragma unroll
    for (int c4 = 0; c4 < 16; ++c4){
        float4 bb = bs[c4];
        o[c4] = make_float4(acc[c4*4+0]+bb.x, acc[c4*4+1]+bb.y,
                            acc[c4*4+2]+bb.z, acc[c4*4+3]+bb.w);
    }
}

// ================= helpers =================
__device__ __forceinline__ unsigned mono_f32(float f){
    unsigned u = __float_as_uint(f);
    return ((int)u >= 0) ? (u | 0x80000000u) : ~u;
}
__device__ __forceinline__ float unmono_f32(unsigned v){
    unsigned u = ((int)v < 0) ? (v & 0x7FFFFFFFu) : ~v;
    return __uint_as_float(u);
}
__device__ __forceinline__ unsigned long long mono_f64(double d){
    unsigned long long u = (unsigned long long)__double_as_longlong(d);
    return ((long long)u >= 0) ? (u | 0x8000000000000000ull) : ~u;
}
__device__ __forceinline__ double unmono_f64(unsigned long long v){
    unsigned long long u = ((long long)v < 0) ? (v & 0x7FFFFFFFFFFFFFFFull) : ~v;
    return __longlong_as_double((long long)u);
}
__device__ __forceinline__ int zbin_of(float z, const unsigned* bmin, const unsigned* bmax, int seg){
    float mnz = unmono_f32(bmin[seg*3+2]), mxz = unmono_f32(bmax[seg*3+2]);
    float iv = (float)NB/(mxz-mnz);
    int c = (int)((z-mnz)*iv);
    return c < 0 ? 0 : (c > NB-1 ? NB-1 : c);
}

// ================= z-sort prep =================
__global__ __launch_bounds__(256) void k_bounds(const float4* __restrict__ w1, const float4* __restrict__ w2,
                                                unsigned* __restrict__ bmin, unsigned* __restrict__ bmax){
    int t = blockIdx.x*256 + threadIdx.x;     // 2*BN
    int cloud = (t >= BN) ? 1 : 0;
    int i = cloud ? t - BN : t;
    float4 p = (cloud ? w2 : w1)[i];
    float mn0 = p.x, mn1 = p.y, mn2 = p.z;
    float mx0 = p.x, mx1 = p.y, mx2 = p.z;
    #pragma unroll
    for (int d = 1; d < 64; d <<= 1){
        mn0 = fminf(mn0, __shfl_xor(mn0, d)); mx0 = fmaxf(mx0, __shfl_xor(mx0, d));
        mn1 = fminf(mn1, __shfl_xor(mn1, d)); mx1 = fmaxf(mx1, __shfl_xor(mx1, d));
        mn2 = fminf(mn2, __shfl_xor(mn2, d)); mx2 = fmaxf(mx2, __shfl_xor(mx2, d));
    }
    if ((threadIdx.x & 63) == 0){
        int seg = cloud*4 + (i >> 13), s3 = seg*3;
        atomicMin(&bmin[s3+0], mono_f32(mn0)); atomicMax(&bmax[s3+0], mono_f32(mx0));
        atomicMin(&bmin[s3+1], mono_f32(mn1)); atomicMax(&bmax[s3+1], mono_f32(mx1));
        atomicMin(&bmin[s3+2], mono_f32(mn2)); atomicMax(&bmax[s3+2], mono_f32(mx2));
    }
}

__global__ __launch_bounds__(256) void k_countz(const float4* __restrict__ w1, const float4* __restrict__ w2,
                                                const unsigned* __restrict__ bmin, const unsigned* __restrict__ bmax,
                                                int* __restrict__ counts){
    int t = blockIdx.x*256 + threadIdx.x;     // 2*BN
    int cloud = (t >= BN) ? 1 : 0;
    int i = cloud ? t - BN : t;
    float4 p = (cloud ? w2 : w1)[i];
    int seg = cloud*4 + (i >> 13);
    atomicAdd(&counts[seg*NBP + zbin_of(p.z, bmin, bmax, seg)], 1);
}

__global__ __launch_bounds__(1024) void k_scanz(const int* __restrict__ counts,
                                                int* __restrict__ starts, int* __restrict__ offsets){
    __shared__ int part[1024];
    int seg = blockIdx.x;
    const int* c = counts + (size_t)seg*NBP;
    int* st = starts + (size_t)seg*NBP;
    int* of = offsets + (size_t)seg*NBP;
    int t = threadIdx.x;
    int base = t*4;
    int s = c[base] + c[base+1] + c[base+2] + c[base+3];
    part[t] = s;
    __syncthreads();
    for (int d = 1; d < 1024; d <<= 1){
        int add = (t >= d) ? part[t-d] : 0;
        __syncthreads();
        part[t] += add;
        __syncthreads();
    }
    int run = part[t] - s;        // exclusive
    #pragma unroll
    for (int i = 0; i < 4; ++i){
        st[base+i] = run;
        of[base+i] = run;
        run += c[base+i];
    }
    if (t == 1023) st[NB] = NN;   // sentinel
}

__global__ __launch_bounds__(256) void k_scatterz(const float4* __restrict__ w1, const float4* __restrict__ w2,
                                                  const unsigned* __restrict__ bmin, const unsigned* __restrict__ bmax,
                                                  int* __restrict__ offsets,
                                                  float4* __restrict__ sortedA, int* __restrict__ sortedIdx){
    int t = blockIdx.x*256 + threadIdx.x;     // 2*BN
    int cloud = (t >= BN) ? 1 : 0;
    int i = cloud ? t - BN : t;
    float4 p = (cloud ? w2 : w1)[i];
    int b = i >> 13;
    int seg = cloud*4 + b;
    int pos = atomicAdd(&offsets[seg*NBP + zbin_of(p.z, bmin, bmax, seg)], 1);
    int dst = cloud*BN + b*NN + pos;
    sortedA[dst] = p;
    sortedIdx[dst] = i & (NN-1);
}

// ================= K2: exact 16-NN, z-stripe expansion (round-8 engine) =================
// Block = 64 consecutive z-sorted queries (all 8 waves hold the SAME 64, lane=query).
// Candidates z-sorted (counting sort; within-bin order arbitrary -> output is a pure
// function of the exact f64 key set, so still deterministic). Waves 0-3 scan upward
// stripes k=w mod 4 from c0 (array pos of block median z); waves 4-7 downward.
// Exact stop per wave: all its unscanned candidates have z beyond the next own
// stripe's near edge minus one bin width => distance^2 >= lb^2; stop when
// lb^2 (with slack) > min(own d16, shared d16 estimate) >= final merged 16th.
// Every accepted candidate is f64-verified into the packed-u64 ladder (top_k ties).

#define FSWAP(x,y) { float _a = fminf((x),(y)), _b = fmaxf((x),(y)); (x)=_a; (y)=_b; }
#define INSERT_F(t)                                                         \
    if ((t) < T15){                                                         \
        T15 = (t);                                                          \
        FSWAP(T14,T15) FSWAP(T13,T14) FSWAP(T12,T13) FSWAP(T11,T12)         \
        FSWAP(T10,T11) FSWAP(T9,T10)  FSWAP(T8,T9)   FSWAP(T7,T8)           \
        FSWAP(T6,T7)   FSWAP(T5,T6)   FSWAP(T4,T5)   FSWAP(T3,T4)           \
        FSWAP(T2,T3)   FSWAP(T1,T2)   FSWAP(T0,T1)                          \
    }

#define KSWAP(x,y) { unsigned long long _lo=(x), _hi=(y); bool _sw=_hi<_lo; (y)=_sw?_lo:_hi; (x)=_sw?_hi:_lo; }
#define INSERT_KEY(key)                                                     \
    if ((key) < A15){                                                       \
        A15 = (key);                                                        \
        KSWAP(A14,A15) KSWAP(A13,A14) KSWAP(A12,A13) KSWAP(A11,A12)         \
        KSWAP(A10,A11) KSWAP(A9,A10)  KSWAP(A8,A9)   KSWAP(A7,A8)           \
        KSWAP(A6,A7)   KSWAP(A5,A6)   KSWAP(A4,A5)   KSWAP(A3,A4)           \
        KSWAP(A2,A3)   KSWAP(A1,A2)   KSWAP(A0,A1)                          \
    }

#define FLUSHW()                                                             \
    do {                                                                     \
        for (int s = 0; s < cnt; ++s){                                       \
            int j = stk[s];                                                  \
            float4 c = cb[j];                                                \
            double px = c.x, py = c.y, pz = c.z;                             \
            double pp  = fma(px,px, fma(py,py, pz*pz));                      \
            double dot = fma(qx,px, fma(qy,py, qz*pz));                      \
            double d2 = qq + pp - 2.0*dot;                                   \
            unsigned long long key = (mono_f64(d2) & ~8191ull)               \
                                   | (unsigned long long)(unsigned)cI[j];    \
            INSERT_KEY(key)                                                  \
        }                                                                    \
        cnt = 0;                                                             \
        d16a = (float)unmono_f64(A15);                                       \
        unsigned m = mono_f32(d16a - qq32);                                  \
        unsigned old = atomicMin(&thrsh[lane], m);                           \
        bdt = unmono_f32(old < m ? old : m) + 1e-4f;                         \
    } while(0)

__global__ __launch_bounds__(512, 2) void k_knnz(const float4* __restrict__ sortedA,
                                                 const int* __restrict__ sortedIdx,
                                                 const int* __restrict__ startsZ,
                                                 const unsigned* __restrict__ bmin,
                                                 const unsigned* __restrict__ bmax,
                                                 int* __restrict__ outA, int* __restrict__ outB){
    __shared__ unsigned int thrsh[64];
    __shared__ int c0sh;
    __shared__ __align__(16) char pool[38912];   // stacks (512*19*4) / merge (4*64*17*8)

    int tid = threadIdx.x;
    int lane = tid & 63;
    int wv = tid >> 6;
    int candCloud = (blockIdx.y == 0) ? 1 : 0;   // y0: idx12 (cands=cloud2), y1: idx11
    int* out = (blockIdx.y == 0) ? outA : outB;

    int sp = blockIdx.x*64 + lane;               // sorted query position (cloud1)
    int b = sp >> 13;                            // constant per block
    float4 q = sortedA[sp];
    int qorig = sortedIdx[sp];
    const float4* cb = sortedA + candCloud*BN + b*NN;
    const int*    cI = sortedIdx + candCloud*BN + b*NN;

    int segs = __builtin_amdgcn_readfirstlane(candCloud*4 + b);
    float mnz = unmono_f32(bmin[segs*3+2]);
    float mxz = unmono_f32(bmax[segs*3+2]);
    float binw = (mxz - mnz)*(1.0f/NB) + 1e-6f;

    float medz = __shfl(q.z, 32);
    if (tid < 64) thrsh[tid] = 0xFF800000u;      // mono(+inf)
    if (tid == 0){
        float iv = (float)NB/(mxz-mnz);
        int bin = (int)((medz-mnz)*iv);
        bin = bin < 0 ? 0 : (bin > NB-1 ? NB-1 : bin);
        c0sh = startsZ[(size_t)segs*NBP + bin];
    }
    __syncthreads();
    int c0 = c0sh;
    bool up = (wv < 4);
    int k0 = wv & 3;

    float n2x = -2.f*q.x, n2y = -2.f*q.y, n2z = -2.f*q.z;
    float qq32 = q.w;
    double qx = q.x, qy = q.y, qz = q.z;
    double qq = fma(qx,qx, fma(qy,qy, qz*qz));
    int cnt = 0;

    // ---- Phase A: f32 value-ladder over own first stripe -> seed shared threshold ----
    {
        const float FINF = __builtin_inff();
        float T0=FINF,T1=FINF,T2=FINF,T3=FINF,T4=FINF,T5=FINF,T6=FINF,T7=FINF,
              T8=FINF,T9=FINF,T10=FINF,T11=FINF,T12=FINF,T13=FINF,T14=FINF,T15=FINF;
        float bdtA = FINF;
        float* stkf = ((float*)pool) + tid*SCAP;
        int a = up ? c0 + k0*S : c0 - (k0+1)*S;
        int lo = a < 0 ? 0 : a, hi = (a+S) > NN ? NN : (a+S);
        for (int j = lo; j < hi; ++j){
            float4 c = cb[j];
            float t = fmaf(n2x, c.x, c.w);
            t = fmaf(n2y, c.y, t);
            t = fmaf(n2z, c.z, t);
            if (t < fminf(bdtA, T15)){ stkf[cnt] = t; cnt++; }
            if ((j & 3) == 3 && __any(cnt >= 16)){
                for (int s = 0; s < cnt; ++s){ float t2 = stkf[s]; INSERT_F(t2) }
                cnt = 0;
                unsigned m = mono_f32(T15);
                unsigned old = atomicMin(&thrsh[lane], m);
                bdtA = unmono_f32(old < m ? old : m);
            }
        }
        for (int s = 0; s < cnt; ++s){ float t2 = stkf[s]; INSERT_F(t2) }
        cnt = 0;
        atomicMin(&thrsh[lane], mono_f32(T15));
    }
    __syncthreads();

    // ---- Phase B: exact expansion with f64 verify ----
    const unsigned long long KINIT = 0xFFF0000000000000ull | 8191ull;
    unsigned long long A0=KINIT, A1=KINIT, A2=KINIT, A3=KINIT,
                       A4=KINIT, A5=KINIT, A6=KINIT, A7=KINIT,
                       A8=KINIT, A9=KINIT, A10=KINIT, A11=KINIT,
                       A12=KINIT, A13=KINIT, A14=KINIT, A15=KINIT;
    float d16a = __builtin_inff();
    float bdt = unmono_f32(thrsh[lane]) + 1e-4f;
    int* stk = ((int*)pool) + tid*SCAP;

    for (int k = k0; ; k += 4){
        int a = up ? c0 + k*S : c0 - (k+1)*S;
        if (up ? (a >= NN) : (a + S <= 0)) break;
        int lo = a < 0 ? 0 : a, hi = (a+S) > NN ? NN : (a+S);
        for (int j = lo; j < hi; ++j){
            float4 c = cb[j];
            float t = fmaf(n2x, c.x, c.w);
            t = fmaf(n2y, c.y, t);
            t = fmaf(n2z, c.z, t);
            if (t < bdt){ stk[cnt] = j; cnt++; }
            if ((j & 3) == 3 && __any(cnt >= 16)) FLUSHW();
        }
        if (__any(cnt >= 1)) FLUSHW();
        // refresh + exact stop test
        float ts = unmono_f32(thrsh[lane]);
        bdt = fminf(bdt, ts + 1e-4f);
        float est = fminf(d16a, ts + qq32);      // >= final merged 16th dist^2
        int nidx = up ? (c0 + (k+4)*S) : (c0 - (k+4)*S - 1);
        bool more = up ? (nidx < NN) : (nidx >= 0);
        if (!more) break;
        float zn = cb[nidx].z;
        float lb = up ? fmaxf(zn - binw - q.z, 0.f) : fmaxf(q.z - zn - binw, 0.f);
        if (__all(lb*lb*0.998f - 1e-5f > est)) break;
    }
    FLUSHW();

    __syncthreads();                             // stacks dead; pool becomes merge area
    unsigned long long* mrg = (unsigned long long*)pool;   // [4][64][17]
    #pragma unroll
    for (int r = 4; r >= 1; r >>= 1){
        if (wv >= r && wv < 2*r){
            unsigned long long* dst = mrg + ((size_t)(wv - r)*64 + lane)*17;
            dst[0]=A0;  dst[1]=A1;  dst[2]=A2;  dst[3]=A3;
            dst[4]=A4;  dst[5]=A5;  dst[6]=A6;  dst[7]=A7;
            dst[8]=A8;  dst[9]=A9;  dst[10]=A10; dst[11]=A11;
            dst[12]=A12; dst[13]=A13; dst[14]=A14; dst[15]=A15;
        }
        __syncthreads();
        if (wv < r){
            const unsigned long long* src = mrg + ((size_t)wv*64 + lane)*17;
            for (int i = 0; i < 16; ++i){
                unsigned long long bkey = src[i];
                if (__all(bkey >= A15)) break;       // uniform early-out
                INSERT_KEY(bkey)
            }
        }
        __syncthreads();
    }
    if (wv == 0){
        int4* o = (int4*)(out + ((size_t)(b*NN + qorig))*16);
        o[0] = make_int4((int)(A0 & 8191ull),  (int)(A1 & 8191ull),
                         (int)(A2 & 8191ull),  (int)(A3 & 8191ull));
        o[1] = make_int4((int)(A4 & 8191ull),  (int)(A5 & 8191ull),
                         (int)(A6 & 8191ull),  (int)(A7 & 8191ull));
        o[2] = make_int4((int)(A8 & 8191ull),  (int)(A9 & 8191ull),
                         (int)(A10 & 8191ull), (int)(A11 & 8191ull));
        o[3] = make_int4((int)(A12 & 8191ull), (int)(A13 & 8191ull),
                         (int)(A14 & 8191ull), (int)(A15 & 8191ull));
    }
}

// ---------------- K3: small MLP hidden states H[b,n,k,8] ----------------
__global__ __launch_bounds__(256) void k_h2(const float4* __restrict__ qpts, const float4* __restrict__ cpts,
                                            const int* __restrict__ idx,
                                            const float* __restrict__ w1, const float* __restrict__ b1,
                                            const float* __restrict__ w2, const float* __restrict__ b2,
                                            float* __restrict__ H){
    int i = blockIdx.x*256 + threadIdx.x;   // over BNK
    int gq = i >> 4;
    int b = gq >> 13;
    int m = idx[i];
    float4 p = cpts[b*NN + m];
    float4 q = qpts[gq];
    float x = p.x - q.x, y = p.y - q.y, z = p.z - q.z;
    float h1[8], h2[8];
    #pragma unroll
    for (int j = 0; j < 8; ++j){
        float v = b1[j] + w1[j*3+0]*x + w1[j*3+1]*y + w1[j*3+2]*z;
        h1[j] = fmaxf(v, 0.f);
    }
    #pragma unroll
    for (int j = 0; j < 8; ++j){
        float v = b2[j];
        #pragma unroll
        for (int jj = 0; jj < 8; ++jj) v = fmaf(w2[j*8+jj], h1[jj], v);
        h2[j] = fmaxf(v, 0.f);
    }
    float4* o = (float4*)(H + (size_t)i*8);
    o[0] = make_float4(h2[0],h2[1],h2[2],h2[3]);
    o[1] = make_float4(h2[4],h2[5],h2[6],h2[7]);
}

__device__ __forceinline__ float rl_f(int hb, int lane_c){
    return __int_as_float(__builtin_amdgcn_readlane(hb, lane_c));
}

// ---------------- K4: fused stage 1 -> p2n[b,n,co] ----------------
__global__ __launch_bounds__(256) void k_stage1(const float* __restrict__ A1, const float* __restrict__ A2,
                                                const int* __restrict__ idx12, const float* __restrict__ H12,
                                                const float4* __restrict__ xyzw1, const float4* __restrict__ xyzw2,
                                                const float* __restrict__ W1full, const float* __restrict__ W2,
                                                const float* __restrict__ b2, const float* __restrict__ w3,
                                                const float* __restrict__ b3, float* __restrict__ p2n){
    int lane = threadIdx.x & 63;
    int wv = threadIdx.x >> 6;
    int wgid = blockIdx.x*4 + wv;

    float w2r[64];
    const float4* w2p = (const float4*)(W2 + (size_t)lane*64);
    #pragma unroll
    for (int c4 = 0; c4 < 16; ++c4){
        float4 v = w2p[c4];
        w2r[c4*4+0]=v.x; w2r[c4*4+1]=v.y; w2r[c4*4+2]=v.z; w2r[c4*4+3]=v.w;
    }
    float w1cx = W1full[lane*131+128], w1cy = W1full[lane*131+129], w1cz = W1full[lane*131+130];
    float b2v = b2[lane], b3v = b3[lane];
    float w3r[8];
    {
        const float4* w3p = (const float4*)(w3 + (size_t)lane*8);
        float4 a = w3p[0], bq = w3p[1];
        w3r[0]=a.x; w3r[1]=a.y; w3r[2]=a.z; w3r[3]=a.w;
        w3r[4]=bq.x; w3r[5]=bq.y; w3r[6]=bq.z; w3r[7]=bq.w;
    }

    for (int task = wgid; task < BN; task += 4096){
        int b = task >> 13;
        float4 q = xyzw1[task];
        float a1 = A1[(size_t)task*64 + lane];
        float acc = 0.f;
        const int* ip = idx12 + (size_t)task*16;
        for (int k = 0; k < 16; ++k){
            int m = ip[k];
            float4 p = xyzw2[b*NN + m];
            float a2 = A2[(size_t)(b*NN+m)*64 + lane];
            float h = a1 + a2;
            h = fmaf(w1cx, p.x - q.x, h);
            h = fmaf(w1cy, p.y - q.y, h);
            h = fmaf(w1cz, p.z - q.z, h);
            h = fmaxf(h, 0.1f*h);                 // leaky relu
            int hb = __float_as_int(h);
            float c20 = 0.f, c21 = 0.f, c22 = 0.f, c23 = 0.f;
            #pragma unroll
            for (int c = 0; c < 64; c += 4){
                c20 = fmaf(w2r[c+0], rl_f(hb, c+0), c20);
                c21 = fmaf(w2r[c+1], rl_f(hb, c+1), c21);
                c22 = fmaf(w2r[c+2], rl_f(hb, c+2), c22);
                c23 = fmaf(w2r[c+3], rl_f(hb, c+3), c23);
            }
            float c2 = ((c20 + c21) + (c22 + c23)) + b2v;
            c2 = fmaxf(c2, 0.1f*c2);              // leaky relu
            const float4* hw = (const float4*)(H12 + (size_t)(task*16+k)*8);
            float4 ha = hw[0], hb2 = hw[1];
            float w = b3v;
            w = fmaf(w3r[0], ha.x, w); w = fmaf(w3r[1], ha.y, w);
            w = fmaf(w3r[2], ha.z, w); w = fmaf(w3r[3], ha.w, w);
            w = fmaf(w3r[4], hb2.x, w); w = fmaf(w3r[5], hb2.y, w);
            w = fmaf(w3r[6], hb2.z, w); w = fmaf(w3r[7], hb2.w, w);
            w = fmaxf(w, 0.f);                    // relu
            acc = fmaf(w, c2, acc);
        }
        p2n[(size_t)task*64 + lane] = acc;
    }
}

// ---------------- K5: fused stage 2 -> out[b,co,n] ----------------
__global__ __launch_bounds__(256) void k_stage2(const float* __restrict__ p2n, const int* __restrict__ idx11,
                                                const float* __restrict__ H11, const float* __restrict__ w3,
                                                const float* __restrict__ b3, float* __restrict__ out){
    __shared__ float tl[64*65];
    int lane = threadIdx.x & 63;
    int wv = threadIdx.x >> 6;
    int base = blockIdx.x*64;     // flat (b,n)
    int b = base >> 13;

    float w3r[8];
    {
        const float4* w3p = (const float4*)(w3 + (size_t)lane*8);
        float4 a = w3p[0], bq = w3p[1];
        w3r[0]=a.x; w3r[1]=a.y; w3r[2]=a.z; w3r[3]=a.w;
        w3r[4]=bq.x; w3r[5]=bq.y; w3r[6]=bq.z; w3r[7]=bq.w;
    }
    float b3v = b3[lane];

    for (int i = 0; i < 16; ++i){
        int col = base + wv*16 + i;
        const int* ip = idx11 + (size_t)col*16;
        const float* Hb = H11 + (size_t)col*16*8;
        float acc = 0.f;
        for (int k = 0; k < 16; ++k){
            int m = ip[k];
            float c = p2n[(size_t)(b*NN + m)*64 + lane];
            const float4* hw = (const float4*)(Hb + k*8);
            float4 ha = hw[0], hb2 = hw[1];
            float w = b3v;
            w = fmaf(w3r[0], ha.x, w);  w = fmaf(w3r[1], ha.y, w);
            w = fmaf(w3r[2], ha.z, w);  w = fmaf(w3r[3], ha.w, w);
            w = fmaf(w3r[4], hb2.x, w); w = fmaf(w3r[5], hb2.y, w);
            w = fmaf(w3r[6], hb2.z, w); w = fmaf(w3r[7], hb2.w, w);
            w = fmaxf(w, 0.f);
            acc = fmaf(w, c, acc);
        }
        tl[(wv*16+i)*65 + lane] = acc;
    }
    __syncthreads();
    int n0 = base & (NN-1);
    #pragma unroll
    for (int i = 0; i < 16; ++i){
        int co = i*4 + wv;
        float v = tl[lane*65 + co];
        out[((size_t)b*64 + co)*NN + n0 + lane] = v;
    }
}

extern "C" void kernel_launch(void* const* d_in, const int* in_sizes, int n_in,
                              void* d_out, int out_size, void* d_ws, size_t ws_size,
                              hipStream_t stream) {
    const float* xyz1   = (const float*)d_in[0];
    const float* feat1  = (const float*)d_in[1];
    const float* xyz2   = (const float*)d_in[2];
    const float* feat2  = (const float*)d_in[3];
    const float* cost_w1 = (const float*)d_in[4];
    const float* cost_b1 = (const float*)d_in[5];
    const float* cost_w2 = (const float*)d_in[6];
    const float* cost_b2 = (const float*)d_in[7];
    const float* wn1_w1 = (const float*)d_in[8];
    const float* wn1_b1 = (const float*)d_in[9];
    const float* wn1_w2 = (const float*)d_in[10];
    const float* wn1_b2 = (const float*)d_in[11];
    const float* wn1_w3 = (const float*)d_in[12];
    const float* wn1_b3 = (const float*)d_in[13];
    const float* wn2_w1 = (const float*)d_in[14];
    const float* wn2_b1 = (const float*)d_in[15];
    const float* wn2_w2 = (const float*)d_in[16];
    const float* wn2_b2 = (const float*)d_in[17];
    const float* wn2_w3 = (const float*)d_in[18];
    const float* wn2_b3 = (const float*)d_in[19];

    char* ws = (char*)d_ws;
    float4* xyzw1 = (float4*)(ws + 0);
    float4* xyzw2 = (float4*)(ws + 524288);
    float*  A1    = (float*)(ws + 1048576);
    float*  A2    = (float*)(ws + 9437184);
    int*    idx12 = (int*)  (ws + 17825792);
    int*    idx11 = (int*)  (ws + 19922944);
    float*  H12   = (float*)(ws + 22020096);
    float*  H11   = (float*)(ws + 38797312);
    float*  p2n   = (float*)(ws + 55574528);

    // z-sort structures overlaid on the H12 region (dead until k_h2 runs)
    char* g = ws + 22020096;
    int*      counts    = (int*)     (g + 0);          // 8*NBP*4 = 131328
    int*      startsZ   = (int*)     (g + 131328);     // 131328
    int*      offsets   = (int*)     (g + 262656);     // 131328
    float4*   sortedA   = (float4*)  (g + 393984);     // 2*BN*16 = 1048576
    int*      sortedIdx = (int*)     (g + 1442560);    // 2*BN*4  = 262144
    unsigned* bmin      = (unsigned*)(g + 1704704);    // 96
    unsigned* bmax      = (unsigned*)(g + 1704832);    // 96

    hipMemsetAsync(counts, 0, (size_t)8*NBP*4, stream);
    hipMemsetAsync(bmin, 0xFF, 96, stream);
    hipMemsetAsync(bmax, 0x00, 96, stream);

    k_xyzw<<<256, 256, 0, stream>>>(xyz1, xyz2, xyzw1, xyzw2);
    k_prefeat<<<512, 64, 0, stream>>>(feat1, cost_w1, cost_b1, 0,  A1);
    k_prefeat<<<512, 64, 0, stream>>>(feat2, cost_w1, nullptr, 64, A2);
    k_bounds<<<256, 256, 0, stream>>>(xyzw1, xyzw2, bmin, bmax);
    k_countz<<<256, 256, 0, stream>>>(xyzw1, xyzw2, bmin, bmax, counts);
    k_scanz<<<8, 1024, 0, stream>>>(counts, startsZ, offsets);
    k_scatterz<<<256, 256, 0, stream>>>(xyzw1, xyzw2, bmin, bmax, offsets, sortedA, sortedIdx);
    k_knnz<<<dim3(512, 2), 512, 0, stream>>>(sortedA, sortedIdx, startsZ, bmin, bmax, idx12, idx11);
    k_h2<<<2048, 256, 0, stream>>>(xyzw1, xyzw2, idx12, wn2_w1, wn2_b1, wn2_w2, wn2_b2, H12);
    k_h2<<<2048, 256, 0, stream>>>(xyzw1, xyzw1, idx11, wn1_w1, wn1_b1, wn1_w2, wn1_b2, H11);
    k_stage1<<<1024, 256, 0, stream>>>(A1, A2, idx12, H12, xyzw1, xyzw2,
                                       cost_w1, cost_w2, cost_b2, wn2_w3, wn2_b3, p2n);
    k_stage2<<<512, 256, 0, stream>>>(p2n, idx11, H11, wn1_w3, wn1_b3, (float*)d_out);
}

// Round 13
// 701.469 us; speedup vs baseline: 4.2205x; 1.3637x over previous
//
#include <hip/hip_runtime.h>
#include <stdint.h>

#define BB 4
#define NN 8192
#define KK 16
#define BN (BB*NN)        // 32768
#define BNK (BN*KK)       // 524288

// ---------------- K0: pack xyz -> (x,y,z,|p|^2) float4 ----------------
__global__ void k_xyzw(const float* __restrict__ xyz1, const float* __restrict__ xyz2,
                       float4* __restrict__ w1, float4* __restrict__ w2){
    int t = blockIdx.x*256 + threadIdx.x;
    if (t >= 2*BN) return;
    const float* src; float4* dst; int i;
    if (t < BN){ src = xyz1; dst = w1; i = t; }
    else       { src = xyz2; dst = w2; i = t - BN; }
    int b = i >> 13, m = i & (NN-1);
    const float* p = src + (size_t)b*3*NN + m;
    float x = p[0], y = p[NN], z = p[2*NN];
    dst[i] = make_float4(x, y, z, x*x + y*y + z*z);
}

// ------------- K1: A[b,n,co] = bias[co] + sum_ci W1[co][colOff+ci]*feat[b,ci,n] -------------
__global__ __launch_bounds__(64) void k_prefeat(const float* __restrict__ feat,
                                                const float* __restrict__ W1,
                                                const float* __restrict__ bias, int colOff,
                                                float* __restrict__ out){
    __shared__ float Wt[64*64];   // [ci][co]
    __shared__ float bsh[64];
    int t = threadIdx.x;
    for (int ci = 0; ci < 64; ++ci)
        Wt[ci*64 + t] = W1[t*131 + colOff + ci];   // thread t = row co
    bsh[t] = bias ? bias[t] : 0.0f;
    __syncthreads();

    int col = blockIdx.x*64 + t;       // (b,n) flat
    int b = col >> 13, n = col & (NN-1);
    const float* f = feat + (size_t)b*64*NN + n;
    float acc[64];
    #pragma unroll
    for (int co = 0; co < 64; ++co) acc[co] = 0.f;
    for (int ci = 0; ci < 64; ++ci){
        float v = f[(size_t)ci*NN];
        const float4* wrow = (const float4*)(Wt + ci*64);
        #pragma unroll
        for (int c4 = 0; c4 < 16; ++c4){
            float4 w = wrow[c4];
            acc[c4*4+0] = fmaf(w.x, v, acc[c4*4+0]);
            acc[c4*4+1] = fmaf(w.y, v, acc[c4*4+1]);
            acc[c4*4+2] = fmaf(w.z, v, acc[c4*4+2]);
            acc[c4*4+3] = fmaf(w.w, v, acc[c4*4+3]);
        }
    }
    float4* o = (float4*)(out + (size_t)col*64);
    const float4* bs = (const float4*)bsh;
    #pragma unroll
    for (int c4 = 0; c4 < 16; ++c4){
        float4 bb = bs[c4];
        o[c4] = make_float4(acc[c4*4+0]+bb.x, acc[c4*4+1]+bb.y,
                            acc[c4*4+2]+bb.z, acc[c4*4+3]+bb.w);
    }
}

// ---------------- K2: exact 16-NN, two-phase (round-8 structure + micro-opts) ----------------
// Wave w owns chunk [1024w,1024w+1024) for the block's 64 queries (lane=query).
// Phase A: f32 value-only top-16 of the FIRST 512 of the chunk -> shared
//   per-query screen threshold via LDS atomicMin (any subset's 16th >= full
//   16th => sound). Phase B: full-chunk rescan with tight threshold; survivors
//   f64-verified into packed-u64 register ladder (exact ordering, top_k ties).
// Micro-opts vs r8: branchless stack push (no exec-mask dance), flush check
// every 8 candidates (SCAP 24), hoisted screen threshold.
#define SCAP 24
#define CHUNK 1024

__device__ __forceinline__ unsigned mono_f32(float f){
    unsigned u = __float_as_uint(f);
    return ((int)u >= 0) ? (u | 0x80000000u) : ~u;
}
__device__ __forceinline__ float unmono_f32(unsigned v){
    unsigned u = ((int)v < 0) ? (v & 0x7FFFFFFFu) : ~v;
    return __uint_as_float(u);
}
__device__ __forceinline__ unsigned long long mono_f64(double d){
    unsigned long long u = (unsigned long long)__double_as_longlong(d);
    return ((long long)u >= 0) ? (u | 0x8000000000000000ull) : ~u;
}
__device__ __forceinline__ double unmono_f64(unsigned long long v){
    unsigned long long u = ((long long)v < 0) ? (v & 0x7FFFFFFFFFFFFFFFull) : ~v;
    return __longlong_as_double((long long)u);
}

#define FSWAP(x,y) { float _a = fminf((x),(y)), _b = fmaxf((x),(y)); (x)=_a; (y)=_b; }
#define INSERT_F(t)                                                         \
    if ((t) < T15){                                                         \
        T15 = (t);                                                          \
        FSWAP(T14,T15) FSWAP(T13,T14) FSWAP(T12,T13) FSWAP(T11,T12)         \
        FSWAP(T10,T11) FSWAP(T9,T10)  FSWAP(T8,T9)   FSWAP(T7,T8)           \
        FSWAP(T6,T7)   FSWAP(T5,T6)   FSWAP(T4,T5)   FSWAP(T3,T4)           \
        FSWAP(T2,T3)   FSWAP(T1,T2)   FSWAP(T0,T1)                          \
    }

#define KSWAP(x,y) { unsigned long long _lo=(x), _hi=(y); bool _sw=_hi<_lo; (y)=_sw?_lo:_hi; (x)=_sw?_hi:_lo; }
#define INSERT_KEY(key)                                                     \
    if ((key) < A15){                                                       \
        A15 = (key);                                                        \
        KSWAP(A14,A15) KSWAP(A13,A14) KSWAP(A12,A13) KSWAP(A11,A12)         \
        KSWAP(A10,A11) KSWAP(A9,A10)  KSWAP(A8,A9)   KSWAP(A7,A8)           \
        KSWAP(A6,A7)   KSWAP(A5,A6)   KSWAP(A4,A5)   KSWAP(A3,A4)           \
        KSWAP(A2,A3)   KSWAP(A1,A2)   KSWAP(A0,A1)                          \
    }

__global__ __launch_bounds__(512, 2) void k_knn(const float4* __restrict__ qpts,
                                             const float4* __restrict__ cA, const float4* __restrict__ cB,
                                             int* __restrict__ outA, int* __restrict__ outB){
    __shared__ unsigned int thrsh[64];
    __shared__ __align__(16) char pool[49152];   // stacks (512*24*4) / merge (4*64*17*8) unioned

    const float4* cpts = (blockIdx.y == 0) ? cA : cB;
    int* out            = (blockIdx.y == 0) ? outA : outB;

    int tid = threadIdx.x;
    int lane = tid & 63;
    int wv = tid >> 6;
    int gq = blockIdx.x*64 + lane;
    int b = gq >> 13;
    float4 q = qpts[gq];
    float n2x = -2.f*q.x, n2y = -2.f*q.y, n2z = -2.f*q.z;
    double qx = q.x, qy = q.y, qz = q.z;
    double qq = fma(qx,qx, fma(qy,qy, qz*qz));

    if (tid < 64) thrsh[tid] = 0xFF800000u;      // mono(+inf)
    __syncthreads();

    const float4* cb = cpts + (size_t)b*NN;
    int j0beg = wv*CHUNK;
    int cnt = 0;

    // ================= Phase A: f32 top-16 values of first 512 =================
    {
        float T0,T1,T2,T3,T4,T5,T6,T7,T8,T9,T10,T11,T12,T13,T14,T15;
        const float FINF = __builtin_inff();
        T0=FINF;T1=FINF;T2=FINF;T3=FINF;T4=FINF;T5=FINF;T6=FINF;T7=FINF;
        T8=FINF;T9=FINF;T10=FINF;T11=FINF;T12=FINF;T13=FINF;T14=FINF;T15=FINF;
        float bdtA = FINF, scrA = FINF;
        float* stkf = ((float*)pool) + tid*SCAP;

        for (int j0 = j0beg; j0 < j0beg + 512; j0 += 8){
            const float4* cp = cb + j0;
            #pragma unroll
            for (int jj = 0; jj < 8; ++jj){
                float4 c = cp[jj];
                float t = fmaf(n2x, c.x, c.w);
                t = fmaf(n2y, c.y, t);
                t = fmaf(n2z, c.z, t);
                stkf[cnt] = t;                   // branchless push
                cnt += (t < scrA) ? 1 : 0;
            }
            if (__any(cnt >= 16)){               // growth <=8/check -> cnt <= 23
                for (int s = 0; s < cnt; ++s){ float t2 = stkf[s]; INSERT_F(t2) }
                cnt = 0;
                unsigned m = mono_f32(T15);
                unsigned old = atomicMin(&thrsh[lane], m);
                bdtA = unmono_f32(old < m ? old : m);
                scrA = fminf(bdtA, T15);
            }
        }
        for (int s = 0; s < cnt; ++s){ float t2 = stkf[s]; INSERT_F(t2) }
        cnt = 0;
        atomicMin(&thrsh[lane], mono_f32(T15));
    }
    __syncthreads();     // all Phase-A thresholds published

    // ================= Phase B: exact full-chunk rescan =================
    const unsigned long long KINIT = 0xFFF0000000000000ull | 8191ull;  // mono(+inf)|idx
    unsigned long long A0=KINIT, A1=KINIT, A2=KINIT, A3=KINIT,
                       A4=KINIT, A5=KINIT, A6=KINIT, A7=KINIT,
                       A8=KINIT, A9=KINIT, A10=KINIT, A11=KINIT,
                       A12=KINIT, A13=KINIT, A14=KINIT, A15=KINIT;
    float bdt = unmono_f32(thrsh[lane]) + 1e-4f;   // margin >> f32 screen error
    int* stk = ((int*)pool) + tid*SCAP;

    #define FLUSH_B()                                                            \
        do {                                                                     \
            for (int s = 0; s < cnt; ++s){                                       \
                int j = stk[s];                                                  \
                float4 c = cb[j];                                                \
                double px = c.x, py = c.y, pz = c.z;                             \
                double pp  = fma(px,px, fma(py,py, pz*pz));                      \
                double dot = fma(qx,px, fma(qy,py, qz*pz));                      \
                double d2 = qq + pp - 2.0*dot;                                   \
                unsigned long long key =                                         \
                    (mono_f64(d2) & ~8191ull) | (unsigned long long)(unsigned)j; \
                INSERT_KEY(key)                                                  \
            }                                                                    \
            cnt = 0;                                                             \
            bdt = fminf(bdt, (float)(unmono_f64(A15) - qq) + 1e-4f);             \
        } while(0)

    for (int j0 = j0beg; j0 < j0beg + CHUNK; j0 += 8){
        const float4* cp = cb + j0;
        #pragma unroll
        for (int jj = 0; jj < 8; ++jj){
            float4 c = cp[jj];
            float t = fmaf(n2x, c.x, c.w);
            t = fmaf(n2y, c.y, t);
            t = fmaf(n2z, c.z, t);
            stk[cnt] = j0 + jj;                  // branchless push
            cnt += (t < bdt) ? 1 : 0;
        }
        if (__any(cnt >= 16)) FLUSH_B();         // growth <=8/check -> cnt <= 23
    }
    FLUSH_B();

    __syncthreads();                             // stacks dead; pool becomes merge area
    unsigned long long* mrg = (unsigned long long*)pool;   // [4][64][17]
    #pragma unroll
    for (int r = 4; r >= 1; r >>= 1){
        if (wv >= r && wv < 2*r){
            unsigned long long* dst = mrg + ((size_t)(wv - r)*64 + lane)*17;
            dst[0]=A0;  dst[1]=A1;  dst[2]=A2;  dst[3]=A3;
            dst[4]=A4;  dst[5]=A5;  dst[6]=A6;  dst[7]=A7;
            dst[8]=A8;  dst[9]=A9;  dst[10]=A10; dst[11]=A11;
            dst[12]=A12; dst[13]=A13; dst[14]=A14; dst[15]=A15;
        }
        __syncthreads();
        if (wv < r){
            const unsigned long long* src = mrg + ((size_t)wv*64 + lane)*17;
            for (int i = 0; i < 16; ++i){
                unsigned long long bkey = src[i];
                if (__all(bkey >= A15)) break;       // uniform early-out
                INSERT_KEY(bkey)
            }
        }
        __syncthreads();
    }
    if (wv == 0){
        int4* o = (int4*)(out + (size_t)gq*16);
        o[0] = make_int4((int)(A0 & 8191ull),  (int)(A1 & 8191ull),
                         (int)(A2 & 8191ull),  (int)(A3 & 8191ull));
        o[1] = make_int4((int)(A4 & 8191ull),  (int)(A5 & 8191ull),
                         (int)(A6 & 8191ull),  (int)(A7 & 8191ull));
        o[2] = make_int4((int)(A8 & 8191ull),  (int)(A9 & 8191ull),
                         (int)(A10 & 8191ull), (int)(A11 & 8191ull));
        o[3] = make_int4((int)(A12 & 8191ull), (int)(A13 & 8191ull),
                         (int)(A14 & 8191ull), (int)(A15 & 8191ull));
    }
}

// ---------------- K3: small MLP hidden states H[b,n,k,8] ----------------
__global__ __launch_bounds__(256) void k_h2(const float4* __restrict__ qpts, const float4* __restrict__ cpts,
                                            const int* __restrict__ idx,
                                            const float* __restrict__ w1, const float* __restrict__ b1,
                                            const float* __restrict__ w2, const float* __restrict__ b2,
                                            float* __restrict__ H){
    int i = blockIdx.x*256 + threadIdx.x;   // over BNK
    int gq = i >> 4;
    int b = gq >> 13;
    int m = idx[i];
    float4 p = cpts[b*NN + m];
    float4 q = qpts[gq];
    float x = p.x - q.x, y = p.y - q.y, z = p.z - q.z;
    float h1[8], h2[8];
    #pragma unroll
    for (int j = 0; j < 8; ++j){
        float v = b1[j] + w1[j*3+0]*x + w1[j*3+1]*y + w1[j*3+2]*z;
        h1[j] = fmaxf(v, 0.f);
    }
    #pragma unroll
    for (int j = 0; j < 8; ++j){
        float v = b2[j];
        #pragma unroll
        for (int jj = 0; jj < 8; ++jj) v = fmaf(w2[j*8+jj], h1[jj], v);
        h2[j] = fmaxf(v, 0.f);
    }
    float4* o = (float4*)(H + (size_t)i*8);
    o[0] = make_float4(h2[0],h2[1],h2[2],h2[3]);
    o[1] = make_float4(h2[4],h2[5],h2[6],h2[7]);
}

__device__ __forceinline__ float rl_f(int hb, int lane_c){
    return __int_as_float(__builtin_amdgcn_readlane(hb, lane_c));
}

// ---------------- K4: fused stage 1 -> p2n[b,n,co] ----------------
__global__ __launch_bounds__(256) void k_stage1(const float* __restrict__ A1, const float* __restrict__ A2,
                                                const int* __restrict__ idx12, const float* __restrict__ H12,
                                                const float4* __restrict__ xyzw1, const float4* __restrict__ xyzw2,
                                                const float* __restrict__ W1full, const float* __restrict__ W2,
                                                const float* __restrict__ b2, const float* __restrict__ w3,
                                                const float* __restrict__ b3, float* __restrict__ p2n){
    int lane = threadIdx.x & 63;
    int wv = threadIdx.x >> 6;
    int wgid = blockIdx.x*4 + wv;

    float w2r[64];
    const float4* w2p = (const float4*)(W2 + (size_t)lane*64);
    #pragma unroll
    for (int c4 = 0; c4 < 16; ++c4){
        float4 v = w2p[c4];
        w2r[c4*4+0]=v.x; w2r[c4*4+1]=v.y; w2r[c4*4+2]=v.z; w2r[c4*4+3]=v.w;
    }
    float w1cx = W1full[lane*131+128], w1cy = W1full[lane*131+129], w1cz = W1full[lane*131+130];
    float b2v = b2[lane], b3v = b3[lane];
    float w3r[8];
    {
        const float4* w3p = (const float4*)(w3 + (size_t)lane*8);
        float4 a = w3p[0], bq = w3p[1];
        w3r[0]=a.x; w3r[1]=a.y; w3r[2]=a.z; w3r[3]=a.w;
        w3r[4]=bq.x; w3r[5]=bq.y; w3r[6]=bq.z; w3r[7]=bq.w;
    }

    for (int task = wgid; task < BN; task += 4096){
        int b = task >> 13;
        float4 q = xyzw1[task];
        float a1 = A1[(size_t)task*64 + lane];
        float acc = 0.f;
        const int* ip = idx12 + (size_t)task*16;
        for (int k = 0; k < 16; ++k){
            int m = ip[k];
            float4 p = xyzw2[b*NN + m];
            float a2 = A2[(size_t)(b*NN+m)*64 + lane];
            float h = a1 + a2;
            h = fmaf(w1cx, p.x - q.x, h);
            h = fmaf(w1cy, p.y - q.y, h);
            h = fmaf(w1cz, p.z - q.z, h);
            h = fmaxf(h, 0.1f*h);                 // leaky relu
            int hb = __float_as_int(h);
            float c20 = 0.f, c21 = 0.f, c22 = 0.f, c23 = 0.f;
            #pragma unroll
            for (int c = 0; c < 64; c += 4){
                c20 = fmaf(w2r[c+0], rl_f(hb, c+0), c20);
                c21 = fmaf(w2r[c+1], rl_f(hb, c+1), c21);
                c22 = fmaf(w2r[c+2], rl_f(hb, c+2), c22);
                c23 = fmaf(w2r[c+3], rl_f(hb, c+3), c23);
            }
            float c2 = ((c20 + c21) + (c22 + c23)) + b2v;
            c2 = fmaxf(c2, 0.1f*c2);              // leaky relu
            const float4* hw = (const float4*)(H12 + (size_t)(task*16+k)*8);
            float4 ha = hw[0], hb2 = hw[1];
            float w = b3v;
            w = fmaf(w3r[0], ha.x, w); w = fmaf(w3r[1], ha.y, w);
            w = fmaf(w3r[2], ha.z, w); w = fmaf(w3r[3], ha.w, w);
            w = fmaf(w3r[4], hb2.x, w); w = fmaf(w3r[5], hb2.y, w);
            w = fmaf(w3r[6], hb2.z, w); w = fmaf(w3r[7], hb2.w, w);
            w = fmaxf(w, 0.f);                    // relu
            acc = fmaf(w, c2, acc);
        }
        p2n[(size_t)task*64 + lane] = acc;
    }
}

// ---------------- K5: fused stage 2 -> out[b,co,n] ----------------
__global__ __launch_bounds__(256) void k_stage2(const float* __restrict__ p2n, const int* __restrict__ idx11,
                                                const float* __restrict__ H11, const float* __restrict__ w3,
                                                const float* __restrict__ b3, float* __restrict__ out){
    __shared__ float tl[64*65];
    int lane = threadIdx.x & 63;
    int wv = threadIdx.x >> 6;
    int base = blockIdx.x*64;     // flat (b,n)
    int b = base >> 13;

    float w3r[8];
    {
        const float4* w3p = (const float4*)(w3 + (size_t)lane*8);
        float4 a = w3p[0], bq = w3p[1];
        w3r[0]=a.x; w3r[1]=a.y; w3r[2]=a.z; w3r[3]=a.w;
        w3r[4]=bq.x; w3r[5]=bq.y; w3r[6]=bq.z; w3r[7]=bq.w;
    }
    float b3v = b3[lane];

    for (int i = 0; i < 16; ++i){
        int col = base + wv*16 + i;
        const int* ip = idx11 + (size_t)col*16;
        const float* Hb = H11 + (size_t)col*16*8;
        float acc = 0.f;
        for (int k = 0; k < 16; ++k){
            int m = ip[k];
            float c = p2n[(size_t)(b*NN + m)*64 + lane];
            const float4* hw = (const float4*)(Hb + k*8);
            float4 ha = hw[0], hb2 = hw[1];
            float w = b3v;
            w = fmaf(w3r[0], ha.x, w);  w = fmaf(w3r[1], ha.y, w);
            w = fmaf(w3r[2], ha.z, w);  w = fmaf(w3r[3], ha.w, w);
            w = fmaf(w3r[4], hb2.x, w); w = fmaf(w3r[5], hb2.y, w);
            w = fmaf(w3r[6], hb2.z, w); w = fmaf(w3r[7], hb2.w, w);
            w = fmaxf(w, 0.f);
            acc = fmaf(w, c, acc);
        }
        tl[(wv*16+i)*65 + lane] = acc;
    }
    __syncthreads();
    int n0 = base & (NN-1);
    #pragma unroll
    for (int i = 0; i < 16; ++i){
        int co = i*4 + wv;
        float v = tl[lane*65 + co];
        out[((size_t)b*64 + co)*NN + n0 + lane] = v;
    }
}

extern "C" void kernel_launch(void* const* d_in, const int* in_sizes, int n_in,
                              void* d_out, int out_size, void* d_ws, size_t ws_size,
                              hipStream_t stream) {
    const float* xyz1   = (const float*)d_in[0];
    const float* feat1  = (const float*)d_in[1];
    const float* xyz2   = (const float*)d_in[2];
    const float* feat2  = (const float*)d_in[3];
    const float* cost_w1 = (const float*)d_in[4];
    const float* cost_b1 = (const float*)d_in[5];
    const float* cost_w2 = (const float*)d_in[6];
    const float* cost_b2 = (const float*)d_in[7];
    const float* wn1_w1 = (const float*)d_in[8];
    const float* wn1_b1 = (const float*)d_in[9];
    const float* wn1_w2 = (const float*)d_in[10];
    const float* wn1_b2 = (const float*)d_in[11];
    const float* wn1_w3 = (const float*)d_in[12];
    const float* wn1_b3 = (const float*)d_in[13];
    const float* wn2_w1 = (const float*)d_in[14];
    const float* wn2_b1 = (const float*)d_in[15];
    const float* wn2_w2 = (const float*)d_in[16];
    const float* wn2_b2 = (const float*)d_in[17];
    const float* wn2_w3 = (const float*)d_in[18];
    const float* wn2_b3 = (const float*)d_in[19];

    char* ws = (char*)d_ws;
    float4* xyzw1 = (float4*)(ws + 0);
    float4* xyzw2 = (float4*)(ws + 524288);
    float*  A1    = (float*)(ws + 1048576);
    float*  A2    = (float*)(ws + 9437184);
    int*    idx12 = (int*)  (ws + 17825792);
    int*    idx11 = (int*)  (ws + 19922944);
    float*  H12   = (float*)(ws + 22020096);
    float*  H11   = (float*)(ws + 38797312);
    float*  p2n   = (float*)(ws + 55574528);

    k_xyzw<<<256, 256, 0, stream>>>(xyz1, xyz2, xyzw1, xyzw2);
    k_prefeat<<<512, 64, 0, stream>>>(feat1, cost_w1, cost_b1, 0,  A1);
    k_prefeat<<<512, 64, 0, stream>>>(feat2, cost_w1, nullptr, 64, A2);
    k_knn<<<dim3(512,2), 512, 0, stream>>>(xyzw1, xyzw2, xyzw1, idx12, idx11);
    k_h2<<<2048, 256, 0, stream>>>(xyzw1, xyzw2, idx12, wn2_w1, wn2_b1, wn2_w2, wn2_b2, H12);
    k_h2<<<2048, 256, 0, stream>>>(xyzw1, xyzw1, idx11, wn1_w1, wn1_b1, wn1_w2, wn1_b2, H11);
    k_stage1<<<1024, 256, 0, stream>>>(A1, A2, idx12, H12, xyzw1, xyzw2,
                                       cost_w1, cost_w2, cost_b2, wn2_w3, wn2_b3, p2n);
    k_stage2<<<512, 256, 0, stream>>>(p2n, idx11, H11, wn1_w3, wn1_b3, (float*)d_out);
}